// Round 4
// baseline (335.449 us; speedup 1.0000x reference)
//
#include <hip/hip_runtime.h>
#include <stdint.h>

#define B_  2
#define S_  2048
#define D_  2048
#define H_  16
#define HD_ 128
#define D3_ 6144

typedef unsigned short u16;
typedef __attribute__((ext_vector_type(8))) __bf16 bf16x8;
typedef __attribute__((ext_vector_type(4))) float f32x4;
typedef __attribute__((ext_vector_type(8))) u16  u16x8;
typedef __attribute__((ext_vector_type(2))) u16  u16x2;

__device__ inline u16 f2bf(float f) {
  union { float f; uint32_t u; } v; v.f = f;
  uint32_t r = v.u + 0x7FFFu + ((v.u >> 16) & 1u);
  return (u16)(r >> 16);
}
__device__ inline float bf2f(u16 u) {
  union { float f; uint32_t u; } v; v.u = ((uint32_t)u) << 16;
  return v.f;
}
__device__ inline void gload_lds16(const void* g, void* l) {
  __builtin_amdgcn_global_load_lds((const __attribute__((address_space(1))) uint32_t*)g,
                                   (__attribute__((address_space(3))) uint32_t*)l, 16, 0, 0);
}

// ---------------- fp32 -> bf16 cast ----------------
__global__ __launch_bounds__(256) void castk(const float* __restrict__ in, u16* __restrict__ out, int n) {
  int i = blockIdx.x * 256 + threadIdx.x;
  int n8 = n >> 3;
  if (i < n8) {
    f32x4 a = ((const f32x4*)in)[2*i];
    f32x4 b = ((const f32x4*)in)[2*i + 1];
    u16x8 o;
#pragma unroll
    for (int j = 0; j < 4; ++j) o[j] = f2bf(a[j]);
#pragma unroll
    for (int j = 0; j < 4; ++j) o[4+j] = f2bf(b[j]);
    ((u16x8*)out)[i] = o;
  }
}

// ---------------- B^T GEMM, phase-pipelined (T2+T3+T4+T5) ----------------
// C[m,n] = sum_k A[m,k]*B[n,k].  BM=256, BN=128, BK=64, 8 waves (4M x 2N),
// per-wave 64x64 (4x4 frags of 16x16x32).  LDS 96KB double-buffered,
// global_load_lds w/ involution source swizzle.  Per K-tile: vmcnt(6)+bar,
// then 4 phases {reads|stage ; bar ; setprio(1) 8xMFMA setprio(0) ; bar}.
template<int BF16OUT>
__global__ __launch_bounds__(512) void gemm_bt2(const u16* __restrict__ A, const u16* __restrict__ Bw,
                                                void* __restrict__ Cp, int M, int N, int K) {
  __shared__ __align__(16) u16 lA[2][256*64];
  __shared__ __align__(16) u16 lB[2][128*64];
  const int tid = threadIdx.x;
  const int w = tid >> 6, l = tid & 63;
  const int lr = l & 15, lg = l >> 4;
  const int nbn = (int)gridDim.x;
  const int nwg = nbn * (int)gridDim.y;
  const int bid = (int)(blockIdx.y * gridDim.x + blockIdx.x);
  const int swz = (bid & 7) * (nwg >> 3) + (bid >> 3);   // XCD swizzle (nwg%8==0)
  const int bm = swz / nbn, bn = swz % nbn;
  const int wr = w >> 1, wc = w & 1;

  f32x4 acc[4][4] = {};

  int arow[4], acol[4], brow[2], bcol[2];
#pragma unroll
  for (int i = 0; i < 4; ++i) {
    int off = i*8192 + tid*16;
    arow[i] = off >> 7;
    acol[i] = (off & 127) ^ ((arow[i] & 7) << 4);
  }
#pragma unroll
  for (int i = 0; i < 2; ++i) {
    int off = i*8192 + tid*16;
    brow[i] = off >> 7;
    bcol[i] = (off & 127) ^ ((brow[i] & 7) << 4);
  }
  const size_t rs = (size_t)K * 2;
  const char* Ab = (const char*)A + (size_t)bm * 256 * rs;
  const char* Bb = (const char*)Bw + (size_t)bn * 128 * rs;

#define STG2(c_, t_) do {                                                            \
    _Pragma("unroll")                                                                \
    for (int i_ = 0; i_ < 4; ++i_)                                                   \
      gload_lds16(Ab + (size_t)arow[i_]*rs + (size_t)(t_)*128 + acol[i_],            \
                  (char*)lA[c_] + i_*8192 + w*1024);                                 \
    _Pragma("unroll")                                                                \
    for (int i_ = 0; i_ < 2; ++i_)                                                   \
      gload_lds16(Bb + (size_t)brow[i_]*rs + (size_t)(t_)*128 + bcol[i_],            \
                  (char*)lB[c_] + i_*8192 + w*1024);                                 \
  } while (0)

  const int NT = K >> 6;
  STG2(0, 0);
  STG2(1, 1);

  for (int t = 0; t < NT; ++t) {
    const int c = t & 1;
    if (t < NT-1) { asm volatile("s_waitcnt vmcnt(6)" ::: "memory"); }   // tile t landed
    else          { asm volatile("s_waitcnt vmcnt(0)" ::: "memory"); }
    __builtin_amdgcn_s_barrier();
    asm volatile("" ::: "memory");
    const char* lAb = (const char*)lA[c];
    const char* lBb = (const char*)lB[c];

    bf16x8 af[4][2], bfr[4][2];

    // ---- P0: reads A mf0-1 + B nf0-1 ; MFMA Q(m01 x n01)
#pragma unroll
    for (int mf = 0; mf < 2; ++mf)
#pragma unroll
      for (int ks = 0; ks < 2; ++ks) {
        int row = wr*64 + mf*16 + lr;
        af[mf][ks] = *(const bf16x8*)(lAb + row*128 + ((ks*64 + lg*16) ^ ((row & 7) << 4)));
      }
#pragma unroll
    for (int nf = 0; nf < 2; ++nf)
#pragma unroll
      for (int ks = 0; ks < 2; ++ks) {
        int row = wc*64 + nf*16 + lr;
        bfr[nf][ks] = *(const bf16x8*)(lBb + row*128 + ((ks*64 + lg*16) ^ ((row & 7) << 4)));
      }
    __builtin_amdgcn_s_barrier();
    __builtin_amdgcn_sched_barrier(0);
    __builtin_amdgcn_s_setprio(1);
#pragma unroll
    for (int mf = 0; mf < 2; ++mf)
#pragma unroll
      for (int nf = 0; nf < 2; ++nf)
#pragma unroll
        for (int ks = 0; ks < 2; ++ks)
          acc[mf][nf] = __builtin_amdgcn_mfma_f32_16x16x32_bf16(af[mf][ks], bfr[nf][ks], acc[mf][nf], 0, 0, 0);
    __builtin_amdgcn_s_setprio(0);
    __builtin_amdgcn_s_barrier();

    // ---- P1: reads B nf2-3 ; MFMA Q(m01 x n23)
#pragma unroll
    for (int nf = 2; nf < 4; ++nf)
#pragma unroll
      for (int ks = 0; ks < 2; ++ks) {
        int row = wc*64 + nf*16 + lr;
        bfr[nf][ks] = *(const bf16x8*)(lBb + row*128 + ((ks*64 + lg*16) ^ ((row & 7) << 4)));
      }
    __builtin_amdgcn_s_barrier();
    __builtin_amdgcn_sched_barrier(0);
    __builtin_amdgcn_s_setprio(1);
#pragma unroll
    for (int mf = 0; mf < 2; ++mf)
#pragma unroll
      for (int nf = 2; nf < 4; ++nf)
#pragma unroll
        for (int ks = 0; ks < 2; ++ks)
          acc[mf][nf] = __builtin_amdgcn_mfma_f32_16x16x32_bf16(af[mf][ks], bfr[nf][ks], acc[mf][nf], 0, 0, 0);
    __builtin_amdgcn_s_setprio(0);
    __builtin_amdgcn_s_barrier();

    // ---- P2: reads A mf2-3 ; MFMA Q(m23 x n01)
#pragma unroll
    for (int mf = 2; mf < 4; ++mf)
#pragma unroll
      for (int ks = 0; ks < 2; ++ks) {
        int row = wr*64 + mf*16 + lr;
        af[mf][ks] = *(const bf16x8*)(lAb + row*128 + ((ks*64 + lg*16) ^ ((row & 7) << 4)));
      }
    __builtin_amdgcn_s_barrier();
    __builtin_amdgcn_sched_barrier(0);
    __builtin_amdgcn_s_setprio(1);
#pragma unroll
    for (int mf = 2; mf < 4; ++mf)
#pragma unroll
      for (int nf = 0; nf < 2; ++nf)
#pragma unroll
        for (int ks = 0; ks < 2; ++ks)
          acc[mf][nf] = __builtin_amdgcn_mfma_f32_16x16x32_bf16(af[mf][ks], bfr[nf][ks], acc[mf][nf], 0, 0, 0);
    __builtin_amdgcn_s_setprio(0);
    __builtin_amdgcn_s_barrier();

    // ---- P3: stage tile t+2 into buf c (all reads of buf c done: P2-exit barrier
    //          followed every wave's lgkm-complete MFMA) ; MFMA Q(m23 x n23)
    if (t < NT-2) STG2(c, t + 2);
    __builtin_amdgcn_s_barrier();
    __builtin_amdgcn_sched_barrier(0);
    __builtin_amdgcn_s_setprio(1);
#pragma unroll
    for (int mf = 2; mf < 4; ++mf)
#pragma unroll
      for (int nf = 2; nf < 4; ++nf)
#pragma unroll
        for (int ks = 0; ks < 2; ++ks)
          acc[mf][nf] = __builtin_amdgcn_mfma_f32_16x16x32_bf16(af[mf][ks], bfr[nf][ks], acc[mf][nf], 0, 0, 0);
    __builtin_amdgcn_s_setprio(0);
    asm volatile("" ::: "memory");
    __builtin_amdgcn_s_barrier();
  }
#undef STG2

#pragma unroll
  for (int mf = 0; mf < 4; ++mf)
#pragma unroll
    for (int nf = 0; nf < 4; ++nf)
#pragma unroll
      for (int j = 0; j < 4; ++j) {
        int m = bm*256 + wr*64 + mf*16 + lg*4 + j;
        int n = bn*128 + wc*64 + nf*16 + lr;
        float v = acc[mf][nf][j];
        if (BF16OUT) ((u16*)Cp)[(size_t)m * N + n] = f2bf(v);
        else         ((float*)Cp)[(size_t)m * N + n] = v;
      }
}

// ---------------- RoPE + per-head L2 norm (+attn_scale*log2e on Q) ----------------
__global__ __launch_bounds__(256) void rope_norm(const u16* __restrict__ qkv, const float* __restrict__ fc,
                                                 const float* __restrict__ scale_p,
                                                 u16* __restrict__ Qo, u16* __restrict__ Ko) {
  int gid = blockIdx.x;
  int bs = gid >> 2;
  int s = bs & (S_ - 1);
  int b = bs >> 11;
  int w = threadIdx.x >> 6, l = threadIdx.x & 63;
  int h = (gid & 3)*4 + w;
  float2 cs = ((const float2*)fc)[(size_t)s*64 + l];
  float scale = scale_p[0] * 1.4426950408889634f;  // fold log2(e) for exp2 softmax
  const u16* base = qkv + (size_t)bs * D3_;
  size_t obase = ((size_t)(b*H_ + h) * S_ + s) * HD_ + 2*l;
  {
    const u16* p = base + h*HD_ + 2*l;
    float x0 = bf2f(p[0]), x1 = bf2f(p[1]);
    float r0 = x0*cs.x - x1*cs.y;
    float r1 = x1*cs.x + x0*cs.y;
    float t = r0*r0 + r1*r1;
#pragma unroll
    for (int mk = 1; mk < 64; mk <<= 1) t += __shfl_xor(t, mk, 64);
    float inv = scale / (sqrtf(t) + 1e-6f);
    u16x2 o; o[0] = f2bf(r0*inv); o[1] = f2bf(r1*inv);
    *(u16x2*)(Qo + obase) = o;
  }
  {
    const u16* p = base + D_ + h*HD_ + 2*l;
    float x0 = bf2f(p[0]), x1 = bf2f(p[1]);
    float r0 = x0*cs.x - x1*cs.y;
    float r1 = x1*cs.x + x0*cs.y;
    float t = r0*r0 + r1*r1;
#pragma unroll
    for (int mk = 1; mk < 64; mk <<= 1) t += __shfl_xor(t, mk, 64);
    float inv = 1.0f / (sqrtf(t) + 1e-6f);
    u16x2 o; o[0] = f2bf(r0*inv); o[1] = f2bf(r1*inv);
    *(u16x2*)(Ko + obase) = o;
  }
}

// ---------------- V transpose: qkv v-slice [B,S,H,HD] -> Vt [B*H, HD, S] ----------------
__global__ __launch_bounds__(256) void v_trans(const u16* __restrict__ qkv, u16* __restrict__ Vt) {
  __shared__ u16 vt[64][136];
  int blk = blockIdx.x;
  int bh = blk >> 5, st = blk & 31;
  int b = bh >> 4, h = bh & 15;
  int s0 = st * 64;
  int tid = threadIdx.x;
#pragma unroll
  for (int i = 0; i < 4; ++i) {
    int idx = tid + i*256;
    int row = idx >> 4, ch = idx & 15;
    u16x8 v = *(const u16x8*)(qkv + (size_t)(b*S_ + s0 + row) * D3_ + 2*D_ + h*HD_ + ch*8);
    *(u16x8*)(&vt[row][ch*8]) = v;
  }
  __syncthreads();
#pragma unroll
  for (int p = 0; p < 2; ++p) {
    int d = p*64 + (tid >> 2);
    int q = (tid & 3) * 16;
    u16x8 t0, t1;
#pragma unroll
    for (int i = 0; i < 8; ++i) t0[i] = vt[q + i][d];
#pragma unroll
    for (int i = 0; i < 8; ++i) t1[i] = vt[q + 8 + i][d];
    u16* dst = Vt + ((size_t)bh * HD_ + d) * S_ + s0 + q;
    *(u16x8*)dst = t0;
    *(u16x8*)(dst + 8) = t1;
  }
}

// ---------------- causal flash attention ----------------
// QBLK=128, 8 waves (512 thr), KBLK=64. K double-buffered, V single-buffered.
// Counted vmcnt, never 0 except last tile. setprio around MFMA clusters (T5).
__global__ __launch_bounds__(512) void flash_attn(const u16* __restrict__ Qh, const u16* __restrict__ Kh,
                                                  const u16* __restrict__ Vt, u16* __restrict__ AO) {
  __shared__ __align__(16) u16 lK[2][64*128];   // 32 KB
  __shared__ __align__(16) u16 lV[128*64];      // 16 KB
  __shared__ __align__(16) u16 lP[8][16*72];    // 18 KB
  const int i0 = (int)blockIdx.x;               // 0..511
  const int k5 = i0 & 255;
  const int bh = k5 >> 3;
  const int jj = k5 & 7;
  const int qt = (i0 < 256) ? (15 - jj) : jj;   // heavy half first
  const int tid = threadIdx.x, w = tid >> 6, l = tid & 63;
  const int lr = l & 15, lg = l >> 4;
  const int b = bh >> 4, h = bh & 15;

  bf16x8 qf[4];
  {
    const u16* qp = Qh + ((size_t)bh * S_ + qt*128 + w*16 + lr) * HD_ + lg*8;
#pragma unroll
    for (int ks = 0; ks < 4; ++ks) qf[ks] = *(const bf16x8*)(qp + ks*32);
  }
  float m[4], ls[4];
  f32x4 oacc[8] = {};
#pragma unroll
  for (int j = 0; j < 4; ++j) { m[j] = -__builtin_inff(); ls[j] = 0.f; }

  int krow[2], kcol[2], vrow[2], vcol[2], dstb[2];
#pragma unroll
  for (int p = 0; p < 2; ++p) {
    int off = p*8192 + tid*16;
    krow[p] = off >> 8; kcol[p] = (off & 255) ^ ((krow[p] & 7) << 4);
    vrow[p] = off >> 7; vcol[p] = (off & 127) ^ ((vrow[p] & 7) << 4);
    dstb[p] = p*8192 + w*1024;
  }
  const char* Kb = (const char*)(Kh + (size_t)bh * S_ * HD_);
  const char* Vb = (const char*)(Vt + (size_t)bh * HD_ * S_);

#define STAGE_K(nb, kt_) do {                                                       \
    _Pragma("unroll")                                                               \
    for (int p_ = 0; p_ < 2; ++p_)                                                  \
      gload_lds16(Kb + (size_t)((kt_)*64 + krow[p_])*256 + kcol[p_],                \
                  (char*)lK[nb] + dstb[p_]);                                        \
  } while (0)
#define STAGE_V(kt_) do {                                                           \
    _Pragma("unroll")                                                               \
    for (int p_ = 0; p_ < 2; ++p_)                                                  \
      gload_lds16(Vb + (size_t)vrow[p_]*(S_*2) + (kt_)*128 + vcol[p_],              \
                  (char*)lV + dstb[p_]);                                            \
  } while (0)

  const int nt = 2*qt + 2;
  STAGE_K(0, 0);
  STAGE_V(0);
  int cur = 0;
  for (int kt = 0; kt < nt; ++kt) {
    asm volatile("s_waitcnt vmcnt(2)" ::: "memory");
    __builtin_amdgcn_s_barrier();
    asm volatile("" ::: "memory");
    const char* lKb = (const char*)lK[cur];

    // QK^T
    f32x4 sc[4] = {};
    __builtin_amdgcn_s_setprio(1);
#pragma unroll
    for (int f = 0; f < 4; ++f) {
      int row = f*16 + lr;
#pragma unroll
      for (int ks = 0; ks < 4; ++ks) {
        bf16x8 kf = *(const bf16x8*)(lKb + row*256 + ((ks*64 + lg*16) ^ ((row & 7) << 4)));
        sc[f] = __builtin_amdgcn_mfma_f32_16x16x32_bf16(qf[ks], kf, sc[f], 0, 0, 0);
      }
    }
    __builtin_amdgcn_s_setprio(0);
    if (kt < nt-1) STAGE_K(cur ^ 1, kt + 1);   // prefetch next K under softmax

    if (kt >= nt-2) {  // diagonal tiles only
#pragma unroll
      for (int f = 0; f < 4; ++f)
#pragma unroll
        for (int j = 0; j < 4; ++j)
          if (kt*64 + f*16 + lr > qt*128 + w*16 + lg*4 + j) sc[f][j] = -__builtin_inff();
    }
    // online softmax (base-2; log2e folded into Q)
    float rm[4], resc[4], rowp[4];
#pragma unroll
    for (int j = 0; j < 4; ++j) {
      rm[j] = fmaxf(fmaxf(sc[0][j], sc[1][j]), fmaxf(sc[2][j], sc[3][j]));
      rm[j] = fmaxf(rm[j], __shfl_xor(rm[j], 1, 64));
      rm[j] = fmaxf(rm[j], __shfl_xor(rm[j], 2, 64));
      rm[j] = fmaxf(rm[j], __shfl_xor(rm[j], 4, 64));
      rm[j] = fmaxf(rm[j], __shfl_xor(rm[j], 8, 64));
      float mn = fmaxf(m[j], rm[j]);
      resc[j] = exp2f(m[j] - mn);
      m[j] = mn;
      rowp[j] = 0.f;
    }
#pragma unroll
    for (int f = 0; f < 4; ++f)
#pragma unroll
      for (int j = 0; j < 4; ++j) {
        float p = exp2f(sc[f][j] - m[j]);
        sc[f][j] = p;
        rowp[j] += p;
      }
#pragma unroll
    for (int j = 0; j < 4; ++j) {
      rowp[j] += __shfl_xor(rowp[j], 1, 64);
      rowp[j] += __shfl_xor(rowp[j], 2, 64);
      rowp[j] += __shfl_xor(rowp[j], 4, 64);
      rowp[j] += __shfl_xor(rowp[j], 8, 64);
      ls[j] = ls[j] * resc[j] + rowp[j];
    }
#pragma unroll
    for (int fd = 0; fd < 8; ++fd)
#pragma unroll
      for (int j = 0; j < 4; ++j) oacc[fd][j] *= resc[j];
    // P -> wave-private LDS
#pragma unroll
    for (int f = 0; f < 4; ++f)
#pragma unroll
      for (int j = 0; j < 4; ++j)
        lP[w][(lg*4 + j)*72 + f*16 + lr] = f2bf(sc[f][j]);

    if (kt < nt-1) { asm volatile("s_waitcnt vmcnt(2)" ::: "memory"); }
    else           { asm volatile("s_waitcnt vmcnt(0)" ::: "memory"); }
    __builtin_amdgcn_s_barrier();
    asm volatile("" ::: "memory");
    // PV
    __builtin_amdgcn_s_setprio(1);
#pragma unroll
    for (int ks = 0; ks < 2; ++ks) {
      bf16x8 pf = *(const bf16x8*)((const char*)lP[w] + lr*144 + ks*64 + lg*16);
#pragma unroll
      for (int fd = 0; fd < 8; ++fd) {
        int row = fd*16 + lr;
        bf16x8 vf = *(const bf16x8*)((const char*)lV + row*128 + ((ks*64 + lg*16) ^ ((row & 7) << 4)));
        oacc[fd] = __builtin_amdgcn_mfma_f32_16x16x32_bf16(pf, vf, oacc[fd], 0, 0, 0);
      }
    }
    __builtin_amdgcn_s_setprio(0);
    asm volatile("" ::: "memory");
    __builtin_amdgcn_s_barrier();
    asm volatile("" ::: "memory");
    if (kt < nt-1) STAGE_V(kt + 1);
    cur ^= 1;
  }
#undef STAGE_K
#undef STAGE_V
  // epilogue
  float invl[4];
#pragma unroll
  for (int j = 0; j < 4; ++j) invl[j] = 1.0f / ls[j];
#pragma unroll
  for (int fd = 0; fd < 8; ++fd)
#pragma unroll
    for (int j = 0; j < 4; ++j) {
      int qq = qt*128 + w*16 + lg*4 + j;
      int dd = fd*16 + lr;
      float v = oacc[fd][j] * invl[j];
      AO[((size_t)b*S_ + qq)*D_ + h*HD_ + dd] = f2bf(v);
    }
}

// ---------------- launch ----------------
extern "C" void kernel_launch(void* const* d_in, const int* in_sizes, int n_in,
                              void* d_out, int out_size, void* d_ws, size_t ws_size,
                              hipStream_t stream) {
  const float* x        = (const float*)d_in[0];
  const float* w_qkv    = (const float*)d_in[1];
  const float* w_out    = (const float*)d_in[2];
  const float* attn_sc  = (const float*)d_in[3];
  const float* freqs    = (const float*)d_in[4];

  if (ws_size < 167772160u) return;  // need 160 MB scratch

  char* ws = (char*)d_ws;
  u16* xbf  = (u16*)(ws);                 //  16 MB  [4096][2048]
  u16* wqbf = (u16*)(ws + 16777216);      //  24 MB  [6144][2048]
  u16* wobf = (u16*)(ws + 41943040);      //   8 MB  [2048][2048]
  u16* qkv  = (u16*)(ws + 50331648);      //  48 MB  [4096][6144]
  u16* Qh   = (u16*)(ws + 100663296);     //  16 MB  [B*H][S][HD]
  u16* Kh   = (u16*)(ws + 117440512);     //  16 MB  [B*H][S][HD]
  u16* Vt   = (u16*)(ws + 134217728);     //  16 MB  [B*H][HD][S]
  u16* AO   = (u16*)(ws + 150994944);     //  16 MB  [4096][2048]

  castk<<<4096, 256, 0, stream>>>(x,     xbf,  8388608);
  castk<<<6144, 256, 0, stream>>>(w_qkv, wqbf, 12582912);
  castk<<<2048, 256, 0, stream>>>(w_out, wobf, 4194304);

  // QKV: M=4096 (16 row-tiles of 256), N=6144 (48 col-tiles of 128) -> 768 blocks (3 exact rounds)
  gemm_bt2<1><<<dim3(48, 16), 512, 0, stream>>>(xbf, wqbf, qkv, 4096, 6144, 2048);

  rope_norm<<<16384, 256, 0, stream>>>(qkv, freqs, attn_sc, Qh, Kh);
  v_trans<<<1024, 256, 0, stream>>>(qkv, Vt);

  flash_attn<<<512, 512, 0, stream>>>(Qh, Kh, Vt, AO);

  // out: M=4096, N=2048 -> (16,16) = 256 blocks (1 exact round)
  gemm_bt2<0><<<dim3(16, 16), 512, 0, stream>>>(AO, wobf, (float*)d_out, 4096, 2048, 2048);
}

// Round 5
// 311.900 us; speedup vs baseline: 1.0755x; 1.0755x over previous
//
#include <hip/hip_runtime.h>
#include <stdint.h>

#define B_  2
#define S_  2048
#define D_  2048
#define H_  16
#define HD_ 128
#define D3_ 6144

typedef unsigned short u16;
typedef __attribute__((ext_vector_type(8))) __bf16 bf16x8;
typedef __attribute__((ext_vector_type(4))) float f32x4;
typedef __attribute__((ext_vector_type(8))) u16  u16x8;
typedef __attribute__((ext_vector_type(2))) u16  u16x2;

__device__ inline u16 f2bf(float f) {
  union { float f; uint32_t u; } v; v.f = f;
  uint32_t r = v.u + 0x7FFFu + ((v.u >> 16) & 1u);
  return (u16)(r >> 16);
}
__device__ inline float bf2f(u16 u) {
  union { float f; uint32_t u; } v; v.u = ((uint32_t)u) << 16;
  return v.f;
}
__device__ inline void gload_lds16(const void* g, void* l) {
  __builtin_amdgcn_global_load_lds((const __attribute__((address_space(1))) uint32_t*)g,
                                   (__attribute__((address_space(3))) uint32_t*)l, 16, 0, 0);
}

#define BAR() do { asm volatile("" ::: "memory"); __builtin_amdgcn_s_barrier(); asm volatile("" ::: "memory"); } while (0)

// ---------------- fp32 -> bf16 cast ----------------
__global__ __launch_bounds__(256) void castk(const float* __restrict__ in, u16* __restrict__ out, int n) {
  int i = blockIdx.x * 256 + threadIdx.x;
  int n8 = n >> 3;
  if (i < n8) {
    f32x4 a = ((const f32x4*)in)[2*i];
    f32x4 b = ((const f32x4*)in)[2*i + 1];
    u16x8 o;
#pragma unroll
    for (int j = 0; j < 4; ++j) o[j] = f2bf(a[j]);
#pragma unroll
    for (int j = 0; j < 4; ++j) o[4+j] = f2bf(b[j]);
    ((u16x8*)out)[i] = o;
  }
}

// ============ 8-phase B^T GEMM (m201 geometry): BM=BN=256, BK=64, 8 waves 2Mx4N,
// per-wave 128x64 (24 ds_read_b128 per 64 MFMA). LDS 128KB: A[2dbuf][2half][128x64],
// B same at +64KB. Half-tile staging 1/phase, counted vmcnt(4) once per K-tile. ============
template<int BF16OUT>
__global__ __launch_bounds__(512, 2) void gemm8(const u16* __restrict__ A, const u16* __restrict__ Bw,
                                                void* __restrict__ Cp, int M, int N, int K) {
  __shared__ __align__(16) u16 lds_[65536];   // 128 KB
  char* ldsb = (char*)lds_;
  const int tid = threadIdx.x;
  const int w = tid >> 6, l = tid & 63;
  const int lr = l & 15, lg = l >> 4;
  const int wr = w >> 2, wc = w & 3;          // 2 x 4 waves
  const int nbn = (int)gridDim.x;
  const int nwg = nbn * (int)gridDim.y;
  const int bid = (int)(blockIdx.y * gridDim.x + blockIdx.x);
  const int swz = (bid & 7) * (nwg >> 3) + (bid >> 3);   // XCD swizzle (nwg%8==0)
  const int bm = swz / nbn, bn = swz % nbn;

  f32x4 acc[8][4] = {};

  const int srow = tid >> 3;                           // 0..63
  const int scol = ((tid & 7) ^ (srow & 7)) << 4;      // involution source swizzle
  const size_t rs = (size_t)K * 2;
  const char* Ab = (const char*)A + (size_t)bm * 256 * rs;
  const char* Bb = (const char*)Bw + (size_t)bn * 256 * rs;
  const int wb = w * 1024;

  // stage half h (0/1) of tile T_ : 128x64 bf16 = 16KB = 2 gload_lds/thread
#define STG_A(T_, h_) do { \
    const char* s_ = Ab + (size_t)((h_)*128 + srow)*rs + (size_t)(T_)*128 + scol; \
    char* d_ = ldsb + ((((T_)&1)*2 + (h_))*16384) + wb; \
    gload_lds16(s_, d_); gload_lds16(s_ + 64*rs, d_ + 8192); } while (0)
#define STG_B(T_, h_) do { \
    const char* s_ = Bb + (size_t)((h_)*128 + srow)*rs + (size_t)(T_)*128 + scol; \
    char* d_ = ldsb + 65536 + ((((T_)&1)*2 + (h_))*16384) + wb; \
    gload_lds16(s_, d_); gload_lds16(s_ + 64*rs, d_ + 8192); } while (0)

#define RD_A(dst, mf, ks) do { int row_ = (mf)*16 + lr; \
    dst = *(const bf16x8*)(Abase + row_*128 + (((ks)*64 + lg*16) ^ ((row_ & 7) << 4))); } while (0)
#define RD_B(dst, nf, ks) do { int row_ = (wc & 1)*64 + (nf)*16 + lr; \
    dst = *(const bf16x8*)(Bbase + row_*128 + (((ks)*64 + lg*16) ^ ((row_ & 7) << 4))); } while (0)

  const int NT = K >> 6;
  // prologue: tile0 all 4 halves + tile1 B halves (A halves of tile1 staged in-loop q0/q1)
  STG_B(0, 0); STG_B(0, 1); STG_A(0, 0); STG_A(0, 1); STG_B(1, 0); STG_B(1, 1);
  asm volatile("s_waitcnt vmcnt(4)" ::: "memory");   // tile0's 4 halves forced complete
  BAR();

  for (int T = 0; T < NT; ++T) {
    const int db = T & 1;
    const char* Abase = ldsb + (db*2 + wr)*16384;
    const char* Bbase = ldsb + 65536 + (db*2 + (wc >> 1))*16384;
    bf16x8 af[4][2], bfr[4][2];

    // ---- q0: read A mf0-3 + B nf0-1 ; stage A0(T+1) ; MFMA mf0-3 x nf0-1
#pragma unroll
    for (int mf = 0; mf < 4; ++mf) { RD_A(af[mf][0], mf, 0); RD_A(af[mf][1], mf, 1); }
#pragma unroll
    for (int nf = 0; nf < 2; ++nf) { RD_B(bfr[nf][0], nf, 0); RD_B(bfr[nf][1], nf, 1); }
    if (T + 1 < NT) STG_A(T + 1, 0);
    BAR();
    __builtin_amdgcn_s_setprio(1);
#pragma unroll
    for (int mf = 0; mf < 4; ++mf)
#pragma unroll
      for (int nf = 0; nf < 2; ++nf)
#pragma unroll
        for (int ks = 0; ks < 2; ++ks)
          acc[mf][nf] = __builtin_amdgcn_mfma_f32_16x16x32_bf16(af[mf][ks], bfr[nf][ks], acc[mf][nf], 0, 0, 0);
    __builtin_amdgcn_s_setprio(0);
    BAR();

    // ---- q1: read B nf2-3 ; stage A1(T+1) ; MFMA mf0-3 x nf2-3
#pragma unroll
    for (int nf = 2; nf < 4; ++nf) { RD_B(bfr[nf][0], nf, 0); RD_B(bfr[nf][1], nf, 1); }
    if (T + 1 < NT) STG_A(T + 1, 1);
    BAR();
    __builtin_amdgcn_s_setprio(1);
#pragma unroll
    for (int mf = 0; mf < 4; ++mf)
#pragma unroll
      for (int nf = 2; nf < 4; ++nf)
#pragma unroll
        for (int ks = 0; ks < 2; ++ks)
          acc[mf][nf] = __builtin_amdgcn_mfma_f32_16x16x32_bf16(af[mf][ks], bfr[nf][ks], acc[mf][nf], 0, 0, 0);
    __builtin_amdgcn_s_setprio(0);
    BAR();

    // ---- q2: read A mf4-7 ; stage B0(T+2) ; MFMA mf4-7 x nf0-1
#pragma unroll
    for (int mf = 0; mf < 4; ++mf) { RD_A(af[mf][0], mf + 4, 0); RD_A(af[mf][1], mf + 4, 1); }
    if (T + 2 < NT) STG_B(T + 2, 0);
    BAR();
    __builtin_amdgcn_s_setprio(1);
#pragma unroll
    for (int mf = 0; mf < 4; ++mf)
#pragma unroll
      for (int nf = 0; nf < 2; ++nf)
#pragma unroll
        for (int ks = 0; ks < 2; ++ks)
          acc[mf + 4][nf] = __builtin_amdgcn_mfma_f32_16x16x32_bf16(af[mf][ks], bfr[nf][ks], acc[mf + 4][nf], 0, 0, 0);
    __builtin_amdgcn_s_setprio(0);
    BAR();

    // ---- q3: stage B1(T+2) ; vmcnt forces tile T+1 resident ; MFMA mf4-7 x nf2-3
    if (T + 2 < NT) {
      STG_B(T + 2, 1);
      asm volatile("s_waitcnt vmcnt(4)" ::: "memory");   // allow B0/B1(T+2) in flight
    } else if (T + 1 < NT) {
      asm volatile("s_waitcnt vmcnt(0)" ::: "memory");   // tail: drain for last tile
    }
    BAR();
    __builtin_amdgcn_s_setprio(1);
#pragma unroll
    for (int mf = 0; mf < 4; ++mf)
#pragma unroll
      for (int nf = 2; nf < 4; ++nf)
#pragma unroll
        for (int ks = 0; ks < 2; ++ks)
          acc[mf + 4][nf] = __builtin_amdgcn_mfma_f32_16x16x32_bf16(af[mf][ks], bfr[nf][ks], acc[mf + 4][nf], 0, 0, 0);
    __builtin_amdgcn_s_setprio(0);
    BAR();
  }
#undef STG_A
#undef STG_B
#undef RD_A
#undef RD_B

#pragma unroll
  for (int mf = 0; mf < 8; ++mf)
#pragma unroll
    for (int nf = 0; nf < 4; ++nf)
#pragma unroll
      for (int j = 0; j < 4; ++j) {
        int m = bm*256 + wr*128 + mf*16 + lg*4 + j;
        int n = bn*256 + wc*64 + nf*16 + lr;
        float v = acc[mf][nf][j];
        if (BF16OUT) ((u16*)Cp)[(size_t)m * N + n] = f2bf(v);
        else         ((float*)Cp)[(size_t)m * N + n] = v;
      }
}

// ---------------- 128x128 B^T GEMM (R3 kernel; used for the out-projection) ----------------
template<int BF16OUT>
__global__ __launch_bounds__(256) void gemm_bt(const u16* __restrict__ A, const u16* __restrict__ Bw,
                                               void* __restrict__ Cp, int M, int N, int K) {
  __shared__ u16 lA[128*64];
  __shared__ u16 lB[128*64];
  const int tid = threadIdx.x;
  const int w = tid >> 6, l = tid & 63;
  const int lr = l & 15, lg = l >> 4;
  const int nwg = (int)(gridDim.x * gridDim.y);
  const int bid = (int)(blockIdx.y * gridDim.x + blockIdx.x);
  const int swz = (bid & 7) * (nwg >> 3) + (bid >> 3);
  const int bm = swz / (int)gridDim.x, bn = swz % (int)gridDim.x;
  const int wr = w >> 1, wc = w & 1;

  f32x4 acc[4][4] = {};

  int srow[4], scol[4];
#pragma unroll
  for (int i = 0; i < 4; ++i) {
    int off = (w*4 + i)*1024 + l*16;
    srow[i] = off >> 7;
    scol[i] = (off & 127) ^ ((srow[i] & 7) << 4);
  }
  const size_t rs = (size_t)K * 2;
  const char* Ab = (const char*)A + (size_t)bm * 128 * rs;
  const char* Bb = (const char*)Bw + (size_t)bn * 128 * rs;
  char* lAb = (char*)lA; char* lBb = (char*)lB;

  for (int kt = 0; kt < K; kt += 64) {
#pragma unroll
    for (int i = 0; i < 4; ++i) {
      int dst = (w*4 + i)*1024;
      gload_lds16(Ab + srow[i]*rs + kt*2 + scol[i], lAb + dst);
      gload_lds16(Bb + srow[i]*rs + kt*2 + scol[i], lBb + dst);
    }
    __syncthreads();
#pragma unroll
    for (int ks = 0; ks < 2; ++ks) {
      bf16x8 af[4], bfr[4];
#pragma unroll
      for (int mt = 0; mt < 4; ++mt) {
        int row = wr*64 + mt*16 + lr;
        af[mt] = *(const bf16x8*)(lAb + row*128 + ((ks*64 + lg*16) ^ ((row & 7) << 4)));
      }
#pragma unroll
      for (int nt = 0; nt < 4; ++nt) {
        int row = wc*64 + nt*16 + lr;
        bfr[nt] = *(const bf16x8*)(lBb + row*128 + ((ks*64 + lg*16) ^ ((row & 7) << 4)));
      }
#pragma unroll
      for (int mt = 0; mt < 4; ++mt)
#pragma unroll
        for (int nt = 0; nt < 4; ++nt)
          acc[mt][nt] = __builtin_amdgcn_mfma_f32_16x16x32_bf16(af[mt], bfr[nt], acc[mt][nt], 0, 0, 0);
    }
    __syncthreads();
  }
#pragma unroll
  for (int mt = 0; mt < 4; ++mt)
#pragma unroll
    for (int nt = 0; nt < 4; ++nt)
#pragma unroll
      for (int j = 0; j < 4; ++j) {
        int m = bm*128 + wr*64 + mt*16 + lg*4 + j;
        int n = bn*128 + wc*64 + nt*16 + lr;
        float v = acc[mt][nt][j];
        if (BF16OUT) ((u16*)Cp)[(size_t)m * N + n] = f2bf(v);
        else         ((float*)Cp)[(size_t)m * N + n] = v;
      }
}

// ---------------- RoPE + per-head L2 norm (+attn_scale*log2e on Q) ----------------
__global__ __launch_bounds__(256) void rope_norm(const u16* __restrict__ qkv, const float* __restrict__ fc,
                                                 const float* __restrict__ scale_p,
                                                 u16* __restrict__ Qo, u16* __restrict__ Ko) {
  int gid = blockIdx.x;
  int bs = gid >> 2;
  int s = bs & (S_ - 1);
  int b = bs >> 11;
  int w = threadIdx.x >> 6, l = threadIdx.x & 63;
  int h = (gid & 3)*4 + w;
  float2 cs = ((const float2*)fc)[(size_t)s*64 + l];
  float scale = scale_p[0] * 1.4426950408889634f;  // fold log2(e) for exp2 softmax
  const u16* base = qkv + (size_t)bs * D3_;
  size_t obase = ((size_t)(b*H_ + h) * S_ + s) * HD_ + 2*l;
  {
    const u16* p = base + h*HD_ + 2*l;
    float x0 = bf2f(p[0]), x1 = bf2f(p[1]);
    float r0 = x0*cs.x - x1*cs.y;
    float r1 = x1*cs.x + x0*cs.y;
    float t = r0*r0 + r1*r1;
#pragma unroll
    for (int mk = 1; mk < 64; mk <<= 1) t += __shfl_xor(t, mk, 64);
    float inv = scale / (sqrtf(t) + 1e-6f);
    u16x2 o; o[0] = f2bf(r0*inv); o[1] = f2bf(r1*inv);
    *(u16x2*)(Qo + obase) = o;
  }
  {
    const u16* p = base + D_ + h*HD_ + 2*l;
    float x0 = bf2f(p[0]), x1 = bf2f(p[1]);
    float r0 = x0*cs.x - x1*cs.y;
    float r1 = x1*cs.x + x0*cs.y;
    float t = r0*r0 + r1*r1;
#pragma unroll
    for (int mk = 1; mk < 64; mk <<= 1) t += __shfl_xor(t, mk, 64);
    float inv = 1.0f / (sqrtf(t) + 1e-6f);
    u16x2 o; o[0] = f2bf(r0*inv); o[1] = f2bf(r1*inv);
    *(u16x2*)(Ko + obase) = o;
  }
}

// ---------------- V transpose: qkv v-slice [B,S,H,HD] -> Vt [B*H, HD, S] ----------------
__global__ __launch_bounds__(256) void v_trans(const u16* __restrict__ qkv, u16* __restrict__ Vt) {
  __shared__ u16 vt[64][136];
  int blk = blockIdx.x;
  int bh = blk >> 5, st = blk & 31;
  int b = bh >> 4, h = bh & 15;
  int s0 = st * 64;
  int tid = threadIdx.x;
#pragma unroll
  for (int i = 0; i < 4; ++i) {
    int idx = tid + i*256;
    int row = idx >> 4, ch = idx & 15;
    u16x8 v = *(const u16x8*)(qkv + (size_t)(b*S_ + s0 + row) * D3_ + 2*D_ + h*HD_ + ch*8);
    *(u16x8*)(&vt[row][ch*8]) = v;
  }
  __syncthreads();
#pragma unroll
  for (int p = 0; p < 2; ++p) {
    int d = p*64 + (tid >> 2);
    int q = (tid & 3) * 16;
    u16x8 t0, t1;
#pragma unroll
    for (int i = 0; i < 8; ++i) t0[i] = vt[q + i][d];
#pragma unroll
    for (int i = 0; i < 8; ++i) t1[i] = vt[q + 8 + i][d];
    u16* dst = Vt + ((size_t)bh * HD_ + d) * S_ + s0 + q;
    *(u16x8*)dst = t0;
    *(u16x8*)(dst + 8) = t1;
  }
}

// ---------------- causal flash attention ----------------
// QBLK=128, 8 waves (512 thr), KBLK=64. K double-buffered, V single-buffered.
// Counted vmcnt, never 0 except last tile. setprio around MFMA clusters (T5).
__global__ __launch_bounds__(512) void flash_attn(const u16* __restrict__ Qh, const u16* __restrict__ Kh,
                                                  const u16* __restrict__ Vt, u16* __restrict__ AO) {
  __shared__ __align__(16) u16 lK[2][64*128];   // 32 KB
  __shared__ __align__(16) u16 lV[128*64];      // 16 KB
  __shared__ __align__(16) u16 lP[8][16*72];    // 18 KB
  const int i0 = (int)blockIdx.x;               // 0..511
  const int k5 = i0 & 255;
  const int bh = k5 >> 3;
  const int jj = k5 & 7;
  const int qt = (i0 < 256) ? (15 - jj) : jj;   // heavy half first
  const int tid = threadIdx.x, w = tid >> 6, l = tid & 63;
  const int lr = l & 15, lg = l >> 4;
  const int b = bh >> 4, h = bh & 15;

  bf16x8 qf[4];
  {
    const u16* qp = Qh + ((size_t)bh * S_ + qt*128 + w*16 + lr) * HD_ + lg*8;
#pragma unroll
    for (int ks = 0; ks < 4; ++ks) qf[ks] = *(const bf16x8*)(qp + ks*32);
  }
  float m[4], ls[4];
  f32x4 oacc[8] = {};
#pragma unroll
  for (int j = 0; j < 4; ++j) { m[j] = -__builtin_inff(); ls[j] = 0.f; }

  int krow[2], kcol[2], vrow[2], vcol[2], dstb[2];
#pragma unroll
  for (int p = 0; p < 2; ++p) {
    int off = p*8192 + tid*16;
    krow[p] = off >> 8; kcol[p] = (off & 255) ^ ((krow[p] & 7) << 4);
    vrow[p] = off >> 7; vcol[p] = (off & 127) ^ ((vrow[p] & 7) << 4);
    dstb[p] = p*8192 + w*1024;
  }
  const char* Kb = (const char*)(Kh + (size_t)bh * S_ * HD_);
  const char* Vb = (const char*)(Vt + (size_t)bh * HD_ * S_);

#define STAGE_K(nb, kt_) do {                                                       \
    _Pragma("unroll")                                                               \
    for (int p_ = 0; p_ < 2; ++p_)                                                  \
      gload_lds16(Kb + (size_t)((kt_)*64 + krow[p_])*256 + kcol[p_],                \
                  (char*)lK[nb] + dstb[p_]);                                        \
  } while (0)
#define STAGE_V(kt_) do {                                                           \
    _Pragma("unroll")                                                               \
    for (int p_ = 0; p_ < 2; ++p_)                                                  \
      gload_lds16(Vb + (size_t)vrow[p_]*(S_*2) + (kt_)*128 + vcol[p_],              \
                  (char*)lV + dstb[p_]);                                            \
  } while (0)

  const int nt = 2*qt + 2;
  STAGE_K(0, 0);
  STAGE_V(0);
  int cur = 0;
  for (int kt = 0; kt < nt; ++kt) {
    asm volatile("s_waitcnt vmcnt(2)" ::: "memory");
    __builtin_amdgcn_s_barrier();
    asm volatile("" ::: "memory");
    const char* lKb = (const char*)lK[cur];

    // QK^T
    f32x4 sc[4] = {};
    __builtin_amdgcn_s_setprio(1);
#pragma unroll
    for (int f = 0; f < 4; ++f) {
      int row = f*16 + lr;
#pragma unroll
      for (int ks = 0; ks < 4; ++ks) {
        bf16x8 kf = *(const bf16x8*)(lKb + row*256 + ((ks*64 + lg*16) ^ ((row & 7) << 4)));
        sc[f] = __builtin_amdgcn_mfma_f32_16x16x32_bf16(qf[ks], kf, sc[f], 0, 0, 0);
      }
    }
    __builtin_amdgcn_s_setprio(0);
    if (kt < nt-1) STAGE_K(cur ^ 1, kt + 1);   // prefetch next K under softmax

    if (kt >= nt-2) {  // diagonal tiles only
#pragma unroll
      for (int f = 0; f < 4; ++f)
#pragma unroll
        for (int j = 0; j < 4; ++j)
          if (kt*64 + f*16 + lr > qt*128 + w*16 + lg*4 + j) sc[f][j] = -__builtin_inff();
    }
    // online softmax (base-2; log2e folded into Q)
    float rm[4], resc[4], rowp[4];
#pragma unroll
    for (int j = 0; j < 4; ++j) {
      rm[j] = fmaxf(fmaxf(sc[0][j], sc[1][j]), fmaxf(sc[2][j], sc[3][j]));
      rm[j] = fmaxf(rm[j], __shfl_xor(rm[j], 1, 64));
      rm[j] = fmaxf(rm[j], __shfl_xor(rm[j], 2, 64));
      rm[j] = fmaxf(rm[j], __shfl_xor(rm[j], 4, 64));
      rm[j] = fmaxf(rm[j], __shfl_xor(rm[j], 8, 64));
      float mn = fmaxf(m[j], rm[j]);
      resc[j] = exp2f(m[j] - mn);
      m[j] = mn;
      rowp[j] = 0.f;
    }
#pragma unroll
    for (int f = 0; f < 4; ++f)
#pragma unroll
      for (int j = 0; j < 4; ++j) {
        float p = exp2f(sc[f][j] - m[j]);
        sc[f][j] = p;
        rowp[j] += p;
      }
#pragma unroll
    for (int j = 0; j < 4; ++j) {
      rowp[j] += __shfl_xor(rowp[j], 1, 64);
      rowp[j] += __shfl_xor(rowp[j], 2, 64);
      rowp[j] += __shfl_xor(rowp[j], 4, 64);
      rowp[j] += __shfl_xor(rowp[j], 8, 64);
      ls[j] = ls[j] * resc[j] + rowp[j];
    }
#pragma unroll
    for (int fd = 0; fd < 8; ++fd)
#pragma unroll
      for (int j = 0; j < 4; ++j) oacc[fd][j] *= resc[j];
    // P -> wave-private LDS
#pragma unroll
    for (int f = 0; f < 4; ++f)
#pragma unroll
      for (int j = 0; j < 4; ++j)
        lP[w][(lg*4 + j)*72 + f*16 + lr] = f2bf(sc[f][j]);

    if (kt < nt-1) { asm volatile("s_waitcnt vmcnt(2)" ::: "memory"); }
    else           { asm volatile("s_waitcnt vmcnt(0)" ::: "memory"); }
    __builtin_amdgcn_s_barrier();
    asm volatile("" ::: "memory");
    // PV
    __builtin_amdgcn_s_setprio(1);
#pragma unroll
    for (int ks = 0; ks < 2; ++ks) {
      bf16x8 pf = *(const bf16x8*)((const char*)lP[w] + lr*144 + ks*64 + lg*16);
#pragma unroll
      for (int fd = 0; fd < 8; ++fd) {
        int row = fd*16 + lr;
        bf16x8 vf = *(const bf16x8*)((const char*)lV + row*128 + ((ks*64 + lg*16) ^ ((row & 7) << 4)));
        oacc[fd] = __builtin_amdgcn_mfma_f32_16x16x32_bf16(pf, vf, oacc[fd], 0, 0, 0);
      }
    }
    __builtin_amdgcn_s_setprio(0);
    asm volatile("" ::: "memory");
    __builtin_amdgcn_s_barrier();
    asm volatile("" ::: "memory");
    if (kt < nt-1) STAGE_V(kt + 1);
    cur ^= 1;
  }
#undef STAGE_K
#undef STAGE_V
  // epilogue
  float invl[4];
#pragma unroll
  for (int j = 0; j < 4; ++j) invl[j] = 1.0f / ls[j];
#pragma unroll
  for (int fd = 0; fd < 8; ++fd)
#pragma unroll
    for (int j = 0; j < 4; ++j) {
      int qq = qt*128 + w*16 + lg*4 + j;
      int dd = fd*16 + lr;
      float v = oacc[fd][j] * invl[j];
      AO[((size_t)b*S_ + qq)*D_ + h*HD_ + dd] = f2bf(v);
    }
}

// ---------------- launch ----------------
extern "C" void kernel_launch(void* const* d_in, const int* in_sizes, int n_in,
                              void* d_out, int out_size, void* d_ws, size_t ws_size,
                              hipStream_t stream) {
  const float* x        = (const float*)d_in[0];
  const float* w_qkv    = (const float*)d_in[1];
  const float* w_out    = (const float*)d_in[2];
  const float* attn_sc  = (const float*)d_in[3];
  const float* freqs    = (const float*)d_in[4];

  if (ws_size < 167772160u) return;  // need 160 MB scratch

  char* ws = (char*)d_ws;
  u16* xbf  = (u16*)(ws);                 //  16 MB  [4096][2048]
  u16* wqbf = (u16*)(ws + 16777216);      //  24 MB  [6144][2048]
  u16* wobf = (u16*)(ws + 41943040);      //   8 MB  [2048][2048]
  u16* qkv  = (u16*)(ws + 50331648);      //  48 MB  [4096][6144]
  u16* Qh   = (u16*)(ws + 100663296);     //  16 MB  [B*H][S][HD]
  u16* Kh   = (u16*)(ws + 117440512);     //  16 MB  [B*H][S][HD]
  u16* Vt   = (u16*)(ws + 134217728);     //  16 MB  [B*H][HD][S]
  u16* AO   = (u16*)(ws + 150994944);     //  16 MB  [4096][2048]

  castk<<<4096, 256, 0, stream>>>(x,     xbf,  8388608);
  castk<<<6144, 256, 0, stream>>>(w_qkv, wqbf, 12582912);
  castk<<<2048, 256, 0, stream>>>(w_out, wobf, 4194304);

  // QKV: 256x256 tiles -> (24, 16) = 384 blocks (1.5 rounds of 256 CUs)
  gemm8<1><<<dim3(24, 16), 512, 0, stream>>>(xbf, wqbf, qkv, 4096, 6144, 2048);

  rope_norm<<<16384, 256, 0, stream>>>(qkv, freqs, attn_sc, Qh, Kh);
  v_trans<<<1024, 256, 0, stream>>>(qkv, Vt);

  flash_attn<<<512, 512, 0, stream>>>(Qh, Kh, Vt, AO);

  // out-projection: 128x128 tiles, full-chip grid (16, 32) = 512 blocks
  gemm_bt<0><<<dim3(16, 32), 256, 0, stream>>>(AO, wobf, (float*)d_out, 4096, 2048, 2048);
}

// Round 7
// 309.787 us; speedup vs baseline: 1.0828x; 1.0068x over previous
//
#include <hip/hip_runtime.h>
#include <stdint.h>

#define B_  2
#define S_  2048
#define D_  2048
#define H_  16
#define HD_ 128
#define D3_ 6144

typedef unsigned short u16;
typedef __attribute__((ext_vector_type(8))) __bf16 bf16x8;
typedef __attribute__((ext_vector_type(4))) float f32x4;
typedef __attribute__((ext_vector_type(8))) u16  u16x8;
typedef __attribute__((ext_vector_type(2))) u16  u16x2;

__device__ inline u16 f2bf(float f) {
  union { float f; uint32_t u; } v; v.f = f;
  uint32_t r = v.u + 0x7FFFu + ((v.u >> 16) & 1u);
  return (u16)(r >> 16);
}
__device__ inline float bf2f(u16 u) {
  union { float f; uint32_t u; } v; v.u = ((uint32_t)u) << 16;
  return v.f;
}
__device__ inline void gload_lds16(const void* g, void* l) {
  __builtin_amdgcn_global_load_lds((const __attribute__((address_space(1))) uint32_t*)g,
                                   (__attribute__((address_space(3))) uint32_t*)l, 16, 0, 0);
}

#define BAR() do { asm volatile("" ::: "memory"); __builtin_amdgcn_s_barrier(); asm volatile("" ::: "memory"); } while (0)

// ---------------- fp32 -> bf16 cast ----------------
__global__ __launch_bounds__(256) void castk(const float* __restrict__ in, u16* __restrict__ out, int n) {
  int i = blockIdx.x * 256 + threadIdx.x;
  int n8 = n >> 3;
  if (i < n8) {
    f32x4 a = ((const f32x4*)in)[2*i];
    f32x4 b = ((const f32x4*)in)[2*i + 1];
    u16x8 o;
#pragma unroll
    for (int j = 0; j < 4; ++j) o[j] = f2bf(a[j]);
#pragma unroll
    for (int j = 0; j < 4; ++j) o[4+j] = f2bf(b[j]);
    ((u16x8*)out)[i] = o;
  }
}

// ============ 8-phase B^T GEMM: BM=BN=256, BK=64, 8 waves 2Mx4N, per-wave 128x64.
// Phases split by (mf-half, ks): balanced LDS reads 8/8/4/4 per phase, B-frags
// held in regs across all 4 phases. LDS 128KB 2-dbuf, half-tile staging 1/phase,
// counted vmcnt(4) once per K-tile. ============
template<int BF16OUT>
__global__ __launch_bounds__(512, 2) void gemm8(const u16* __restrict__ A, const u16* __restrict__ Bw,
                                                void* __restrict__ Cp, int M, int N, int K) {
  __shared__ __align__(16) u16 lds_[65536];   // 128 KB
  char* ldsb = (char*)lds_;
  const int tid = threadIdx.x;
  const int w = tid >> 6, l = tid & 63;
  const int lr = l & 15, lg = l >> 4;
  const int wr = w >> 2, wc = w & 3;          // 2 x 4 waves
  const int nbn = (int)gridDim.x;
  const int nwg = nbn * (int)gridDim.y;
  const int bid = (int)(blockIdx.y * gridDim.x + blockIdx.x);
  const int swz = (bid & 7) * (nwg >> 3) + (bid >> 3);   // XCD swizzle (nwg%8==0)
  const int bm = swz / nbn, bn = swz % nbn;

  f32x4 acc[8][4] = {};

  const int srow = tid >> 3;                           // 0..63
  const int scol = ((tid & 7) ^ (srow & 7)) << 4;      // involution source swizzle
  const size_t rs = (size_t)K * 2;
  const char* Ab = (const char*)A + (size_t)bm * 256 * rs;
  const char* Bb = (const char*)Bw + (size_t)bn * 256 * rs;
  const int wb = w * 1024;

  // stage half h (0/1) of tile T_ : 128x64 bf16 = 16KB = 2 gload_lds/thread
#define STG_A(T_, h_) do { \
    const char* s_ = Ab + (size_t)((h_)*128 + srow)*rs + (size_t)(T_)*128 + scol; \
    char* d_ = ldsb + ((((T_)&1)*2 + (h_))*16384) + wb; \
    gload_lds16(s_, d_); gload_lds16(s_ + 64*rs, d_ + 8192); } while (0)
#define STG_B(T_, h_) do { \
    const char* s_ = Bb + (size_t)((h_)*128 + srow)*rs + (size_t)(T_)*128 + scol; \
    char* d_ = ldsb + 65536 + ((((T_)&1)*2 + (h_))*16384) + wb; \
    gload_lds16(s_, d_); gload_lds16(s_ + 64*rs, d_ + 8192); } while (0)

#define RD_A(dst, mf, ks) do { int row_ = (mf)*16 + lr; \
    dst = *(const bf16x8*)(Abase + row_*128 + (((ks)*64 + lg*16) ^ ((row_ & 7) << 4))); } while (0)
#define RD_B(dst, nf, ks) do { int row_ = (wc & 1)*64 + (nf)*16 + lr; \
    dst = *(const bf16x8*)(Bbase + row_*128 + (((ks)*64 + lg*16) ^ ((row_ & 7) << 4))); } while (0)

  const int NT = K >> 6;
  // prologue: tile0 all 4 halves + tile1 B halves (A halves of tile1 staged in-loop q0/q1)
  STG_A(0, 0); STG_A(0, 1); STG_B(0, 0); STG_B(0, 1); STG_B(1, 0); STG_B(1, 1);
  asm volatile("s_waitcnt vmcnt(4)" ::: "memory");   // tile0 forced complete
  BAR();

  for (int T = 0; T < NT; ++T) {
    const int db = T & 1;
    const char* Abase = ldsb + (db*2 + wr)*16384;
    const char* Bbase = ldsb + 65536 + (db*2 + (wc >> 1))*16384;
    bf16x8 a0[4], a1[4], b0[4], b1[4];

    // ---- q0: read A(mf0-3,ks0) + B(nf0-3,ks0) [8]; stage A0(T+1); MFMA mf0-3 x nf0-3 @ks0
#pragma unroll
    for (int mf = 0; mf < 4; ++mf) RD_A(a0[mf], mf, 0);
#pragma unroll
    for (int nf = 0; nf < 4; ++nf) RD_B(b0[nf], nf, 0);
    if (T + 1 < NT) STG_A(T + 1, 0);
    BAR();
    __builtin_amdgcn_s_setprio(1);
#pragma unroll
    for (int mf = 0; mf < 4; ++mf)
#pragma unroll
      for (int nf = 0; nf < 4; ++nf)
        acc[mf][nf] = __builtin_amdgcn_mfma_f32_16x16x32_bf16(a0[mf], b0[nf], acc[mf][nf], 0, 0, 0);
    __builtin_amdgcn_s_setprio(0);
    BAR();

    // ---- q1: read A(mf0-3,ks1) + B(nf0-3,ks1) [8]; stage A1(T+1); MFMA mf0-3 x nf0-3 @ks1
#pragma unroll
    for (int mf = 0; mf < 4; ++mf) RD_A(a1[mf], mf, 1);
#pragma unroll
    for (int nf = 0; nf < 4; ++nf) RD_B(b1[nf], nf, 1);
    if (T + 1 < NT) STG_A(T + 1, 1);
    BAR();
    __builtin_amdgcn_s_setprio(1);
#pragma unroll
    for (int mf = 0; mf < 4; ++mf)
#pragma unroll
      for (int nf = 0; nf < 4; ++nf)
        acc[mf][nf] = __builtin_amdgcn_mfma_f32_16x16x32_bf16(a1[mf], b1[nf], acc[mf][nf], 0, 0, 0);
    __builtin_amdgcn_s_setprio(0);
    BAR();

    // ---- q2: read A(mf4-7,ks0) [4]; stage B0(T+2); MFMA mf4-7 x nf0-3 @ks0 (b0 reused)
#pragma unroll
    for (int mf = 0; mf < 4; ++mf) RD_A(a0[mf], mf + 4, 0);
    if (T + 2 < NT) STG_B(T + 2, 0);
    BAR();
    __builtin_amdgcn_s_setprio(1);
#pragma unroll
    for (int mf = 0; mf < 4; ++mf)
#pragma unroll
      for (int nf = 0; nf < 4; ++nf)
        acc[mf + 4][nf] = __builtin_amdgcn_mfma_f32_16x16x32_bf16(a0[mf], b0[nf], acc[mf + 4][nf], 0, 0, 0);
    __builtin_amdgcn_s_setprio(0);
    BAR();

    // ---- q3: read A(mf4-7,ks1) [4]; stage B1(T+2); vmcnt(4) forces tile T+1 resident;
    //          MFMA mf4-7 x nf0-3 @ks1 (b1 reused)
#pragma unroll
    for (int mf = 0; mf < 4; ++mf) RD_A(a1[mf], mf + 4, 1);
    if (T + 2 < NT) {
      STG_B(T + 2, 1);
      asm volatile("s_waitcnt vmcnt(4)" ::: "memory");   // B(T+2) may stay in flight
    } else if (T + 1 < NT) {
      asm volatile("s_waitcnt vmcnt(0)" ::: "memory");   // tail: drain for last tile
    }
    BAR();
    __builtin_amdgcn_s_setprio(1);
#pragma unroll
    for (int mf = 0; mf < 4; ++mf)
#pragma unroll
      for (int nf = 0; nf < 4; ++nf)
        acc[mf + 4][nf] = __builtin_amdgcn_mfma_f32_16x16x32_bf16(a1[mf], b1[nf], acc[mf + 4][nf], 0, 0, 0);
    __builtin_amdgcn_s_setprio(0);
    BAR();
  }
#undef STG_A
#undef STG_B
#undef RD_A
#undef RD_B

#pragma unroll
  for (int mf = 0; mf < 8; ++mf)
#pragma unroll
    for (int nf = 0; nf < 4; ++nf)
#pragma unroll
      for (int j = 0; j < 4; ++j) {
        int m = bm*256 + wr*128 + mf*16 + lg*4 + j;
        int n = bn*256 + wc*64 + nf*16 + lr;
        float v = acc[mf][nf][j];
        if (BF16OUT) ((u16*)Cp)[(size_t)m * N + n] = f2bf(v);
        else         ((float*)Cp)[(size_t)m * N + n] = v;
      }
}

// ---------------- 128x128 B^T GEMM (out-projection: full-chip 512-block grid) ----------------
template<int BF16OUT>
__global__ __launch_bounds__(256) void gemm_bt(const u16* __restrict__ A, const u16* __restrict__ Bw,
                                               void* __restrict__ Cp, int M, int N, int K) {
  __shared__ u16 lA[128*64];
  __shared__ u16 lB[128*64];
  const int tid = threadIdx.x;
  const int w = tid >> 6, l = tid & 63;
  const int lr = l & 15, lg = l >> 4;
  const int nwg = (int)(gridDim.x * gridDim.y);
  const int bid = (int)(blockIdx.y * gridDim.x + blockIdx.x);
  const int swz = (bid & 7) * (nwg >> 3) + (bid >> 3);
  const int bm = swz / (int)gridDim.x, bn = swz % (int)gridDim.x;
  const int wr = w >> 1, wc = w & 1;

  f32x4 acc[4][4] = {};

  int srow[4], scol[4];
#pragma unroll
  for (int i = 0; i < 4; ++i) {
    int off = (w*4 + i)*1024 + l*16;
    srow[i] = off >> 7;
    scol[i] = (off & 127) ^ ((srow[i] & 7) << 4);
  }
  const size_t rs = (size_t)K * 2;
  const char* Ab = (const char*)A + (size_t)bm * 128 * rs;
  const char* Bb = (const char*)Bw + (size_t)bn * 128 * rs;
  char* lAb = (char*)lA; char* lBb = (char*)lB;

  for (int kt = 0; kt < K; kt += 64) {
#pragma unroll
    for (int i = 0; i < 4; ++i) {
      int dst = (w*4 + i)*1024;
      gload_lds16(Ab + srow[i]*rs + kt*2 + scol[i], lAb + dst);
      gload_lds16(Bb + srow[i]*rs + kt*2 + scol[i], lBb + dst);
    }
    __syncthreads();
#pragma unroll
    for (int ks = 0; ks < 2; ++ks) {
      bf16x8 af[4], bfr[4];
#pragma unroll
      for (int mt = 0; mt < 4; ++mt) {
        int row = wr*64 + mt*16 + lr;
        af[mt] = *(const bf16x8*)(lAb + row*128 + ((ks*64 + lg*16) ^ ((row & 7) << 4)));
      }
#pragma unroll
      for (int nt = 0; nt < 4; ++nt) {
        int row = wc*64 + nt*16 + lr;
        bfr[nt] = *(const bf16x8*)(lBb + row*128 + ((ks*64 + lg*16) ^ ((row & 7) << 4)));
      }
#pragma unroll
      for (int mt = 0; mt < 4; ++mt)
#pragma unroll
        for (int nt = 0; nt < 4; ++nt)
          acc[mt][nt] = __builtin_amdgcn_mfma_f32_16x16x32_bf16(af[mt], bfr[nt], acc[mt][nt], 0, 0, 0);
    }
    __syncthreads();
  }
#pragma unroll
  for (int mt = 0; mt < 4; ++mt)
#pragma unroll
    for (int nt = 0; nt < 4; ++nt)
#pragma unroll
      for (int j = 0; j < 4; ++j) {
        int m = bm*128 + wr*64 + mt*16 + lg*4 + j;
        int n = bn*128 + wc*64 + nt*16 + lr;
        float v = acc[mt][nt][j];
        if (BF16OUT) ((u16*)Cp)[(size_t)m * N + n] = f2bf(v);
        else         ((float*)Cp)[(size_t)m * N + n] = v;
      }
}

// ---------------- RoPE + per-head L2 norm (+attn_scale*log2e on Q) ----------------
__global__ __launch_bounds__(256) void rope_norm(const u16* __restrict__ qkv, const float* __restrict__ fc,
                                                 const float* __restrict__ scale_p,
                                                 u16* __restrict__ Qo, u16* __restrict__ Ko) {
  int gid = blockIdx.x;
  int bs = gid >> 2;
  int s = bs & (S_ - 1);
  int b = bs >> 11;
  int w = threadIdx.x >> 6, l = threadIdx.x & 63;
  int h = (gid & 3)*4 + w;
  float2 cs = ((const float2*)fc)[(size_t)s*64 + l];
  float scale = scale_p[0] * 1.4426950408889634f;  // fold log2(e) for exp2 softmax
  const u16* base = qkv + (size_t)bs * D3_;
  size_t obase = ((size_t)(b*H_ + h) * S_ + s) * HD_ + 2*l;
  {
    const u16* p = base + h*HD_ + 2*l;
    float x0 = bf2f(p[0]), x1 = bf2f(p[1]);
    float r0 = x0*cs.x - x1*cs.y;
    float r1 = x1*cs.x + x0*cs.y;
    float t = r0*r0 + r1*r1;
#pragma unroll
    for (int mk = 1; mk < 64; mk <<= 1) t += __shfl_xor(t, mk, 64);
    float inv = scale / (sqrtf(t) + 1e-6f);
    u16x2 o; o[0] = f2bf(r0*inv); o[1] = f2bf(r1*inv);
    *(u16x2*)(Qo + obase) = o;
  }
  {
    const u16* p = base + D_ + h*HD_ + 2*l;
    float x0 = bf2f(p[0]), x1 = bf2f(p[1]);
    float r0 = x0*cs.x - x1*cs.y;
    float r1 = x1*cs.x + x0*cs.y;
    float t = r0*r0 + r1*r1;
#pragma unroll
    for (int mk = 1; mk < 64; mk <<= 1) t += __shfl_xor(t, mk, 64);
    float inv = 1.0f / (sqrtf(t) + 1e-6f);
    u16x2 o; o[0] = f2bf(r0*inv); o[1] = f2bf(r1*inv);
    *(u16x2*)(Ko + obase) = o;
  }
}

// ---------------- V transpose: qkv v-slice [B,S,H,HD] -> Vt [B*H, HD, S] ----------------
__global__ __launch_bounds__(256) void v_trans(const u16* __restrict__ qkv, u16* __restrict__ Vt) {
  __shared__ u16 vt[64][136];
  int blk = blockIdx.x;
  int bh = blk >> 5, st = blk & 31;
  int b = bh >> 4, h = bh & 15;
  int s0 = st * 64;
  int tid = threadIdx.x;
#pragma unroll
  for (int i = 0; i < 4; ++i) {
    int idx = tid + i*256;
    int row = idx >> 4, ch = idx & 15;
    u16x8 v = *(const u16x8*)(qkv + (size_t)(b*S_ + s0 + row) * D3_ + 2*D_ + h*HD_ + ch*8);
    *(u16x8*)(&vt[row][ch*8]) = v;
  }
  __syncthreads();
#pragma unroll
  for (int p = 0; p < 2; ++p) {
    int d = p*64 + (tid >> 2);
    int q = (tid & 3) * 16;
    u16x8 t0, t1;
#pragma unroll
    for (int i = 0; i < 8; ++i) t0[i] = vt[q + i][d];
#pragma unroll
    for (int i = 0; i < 8; ++i) t1[i] = vt[q + 8 + i][d];
    u16* dst = Vt + ((size_t)bh * HD_ + d) * S_ + s0 + q;
    *(u16x8*)dst = t0;
    *(u16x8*)(dst + 8) = t1;
  }
}

// ---------------- causal flash attention ----------------
// QBLK=128, 8 waves (512 thr), KBLK=64. K double-buffered, V single-buffered.
// Counted vmcnt, never 0 except last tile. setprio around MFMA clusters (T5).
__global__ __launch_bounds__(512) void flash_attn(const u16* __restrict__ Qh, const u16* __restrict__ Kh,
                                                  const u16* __restrict__ Vt, u16* __restrict__ AO) {
  __shared__ __align__(16) u16 lK[2][64*128];   // 32 KB
  __shared__ __align__(16) u16 lV[128*64];      // 16 KB
  __shared__ __align__(16) u16 lP[8][16*72];    // 18 KB
  const int i0 = (int)blockIdx.x;               // 0..511
  const int k5 = i0 & 255;
  const int bh = k5 >> 3;
  const int jj = k5 & 7;
  const int qt = (i0 < 256) ? (15 - jj) : jj;   // heavy half first
  const int tid = threadIdx.x, w = tid >> 6, l = tid & 63;
  const int lr = l & 15, lg = l >> 4;
  const int b = bh >> 4, h = bh & 15;

  bf16x8 qf[4];
  {
    const u16* qp = Qh + ((size_t)bh * S_ + qt*128 + w*16 + lr) * HD_ + lg*8;
#pragma unroll
    for (int ks = 0; ks < 4; ++ks) qf[ks] = *(const bf16x8*)(qp + ks*32);
  }
  float m[4], ls[4];
  f32x4 oacc[8] = {};
#pragma unroll
  for (int j = 0; j < 4; ++j) { m[j] = -__builtin_inff(); ls[j] = 0.f; }

  int krow[2], kcol[2], vrow[2], vcol[2], dstb[2];
#pragma unroll
  for (int p = 0; p < 2; ++p) {
    int off = p*8192 + tid*16;
    krow[p] = off >> 8; kcol[p] = (off & 255) ^ ((krow[p] & 7) << 4);
    vrow[p] = off >> 7; vcol[p] = (off & 127) ^ ((vrow[p] & 7) << 4);
    dstb[p] = p*8192 + w*1024;
  }
  const char* Kb = (const char*)(Kh + (size_t)bh * S_ * HD_);
  const char* Vb = (const char*)(Vt + (size_t)bh * HD_ * S_);

#define STAGE_K(nb, kt_) do {                                                       \
    _Pragma("unroll")                                                               \
    for (int p_ = 0; p_ < 2; ++p_)                                                  \
      gload_lds16(Kb + (size_t)((kt_)*64 + krow[p_])*256 + kcol[p_],                \
                  (char*)lK[nb] + dstb[p_]);                                        \
  } while (0)
#define STAGE_V(kt_) do {                                                           \
    _Pragma("unroll")                                                               \
    for (int p_ = 0; p_ < 2; ++p_)                                                  \
      gload_lds16(Vb + (size_t)vrow[p_]*(S_*2) + (kt_)*128 + vcol[p_],              \
                  (char*)lV + dstb[p_]);                                            \
  } while (0)

  const int nt = 2*qt + 2;
  STAGE_K(0, 0);
  STAGE_V(0);
  int cur = 0;
  for (int kt = 0; kt < nt; ++kt) {
    asm volatile("s_waitcnt vmcnt(2)" ::: "memory");
    __builtin_amdgcn_s_barrier();
    asm volatile("" ::: "memory");
    const char* lKb = (const char*)lK[cur];

    // QK^T
    f32x4 sc[4] = {};
    __builtin_amdgcn_s_setprio(1);
#pragma unroll
    for (int f = 0; f < 4; ++f) {
      int row = f*16 + lr;
#pragma unroll
      for (int ks = 0; ks < 4; ++ks) {
        bf16x8 kf = *(const bf16x8*)(lKb + row*256 + ((ks*64 + lg*16) ^ ((row & 7) << 4)));
        sc[f] = __builtin_amdgcn_mfma_f32_16x16x32_bf16(qf[ks], kf, sc[f], 0, 0, 0);
      }
    }
    __builtin_amdgcn_s_setprio(0);
    if (kt < nt-1) STAGE_K(cur ^ 1, kt + 1);   // prefetch next K under softmax

    if (kt >= nt-2) {  // diagonal tiles only
#pragma unroll
      for (int f = 0; f < 4; ++f)
#pragma unroll
        for (int j = 0; j < 4; ++j)
          if (kt*64 + f*16 + lr > qt*128 + w*16 + lg*4 + j) sc[f][j] = -__builtin_inff();
    }
    // online softmax (base-2; log2e folded into Q)
    float rm[4], resc[4], rowp[4];
#pragma unroll
    for (int j = 0; j < 4; ++j) {
      rm[j] = fmaxf(fmaxf(sc[0][j], sc[1][j]), fmaxf(sc[2][j], sc[3][j]));
      rm[j] = fmaxf(rm[j], __shfl_xor(rm[j], 1, 64));
      rm[j] = fmaxf(rm[j], __shfl_xor(rm[j], 2, 64));
      rm[j] = fmaxf(rm[j], __shfl_xor(rm[j], 4, 64));
      rm[j] = fmaxf(rm[j], __shfl_xor(rm[j], 8, 64));
      float mn = fmaxf(m[j], rm[j]);
      resc[j] = exp2f(m[j] - mn);
      m[j] = mn;
      rowp[j] = 0.f;
    }
#pragma unroll
    for (int f = 0; f < 4; ++f)
#pragma unroll
      for (int j = 0; j < 4; ++j) {
        float p = exp2f(sc[f][j] - m[j]);
        sc[f][j] = p;
        rowp[j] += p;
      }
#pragma unroll
    for (int j = 0; j < 4; ++j) {
      rowp[j] += __shfl_xor(rowp[j], 1, 64);
      rowp[j] += __shfl_xor(rowp[j], 2, 64);
      rowp[j] += __shfl_xor(rowp[j], 4, 64);
      rowp[j] += __shfl_xor(rowp[j], 8, 64);
      ls[j] = ls[j] * resc[j] + rowp[j];
    }
#pragma unroll
    for (int fd = 0; fd < 8; ++fd)
#pragma unroll
      for (int j = 0; j < 4; ++j) oacc[fd][j] *= resc[j];
    // P -> wave-private LDS
#pragma unroll
    for (int f = 0; f < 4; ++f)
#pragma unroll
      for (int j = 0; j < 4; ++j)
        lP[w][(lg*4 + j)*72 + f*16 + lr] = f2bf(sc[f][j]);

    if (kt < nt-1) { asm volatile("s_waitcnt vmcnt(2)" ::: "memory"); }
    else           { asm volatile("s_waitcnt vmcnt(0)" ::: "memory"); }
    __builtin_amdgcn_s_barrier();
    asm volatile("" ::: "memory");
    // PV
    __builtin_amdgcn_s_setprio(1);
#pragma unroll
    for (int ks = 0; ks < 2; ++ks) {
      bf16x8 pf = *(const bf16x8*)((const char*)lP[w] + lr*144 + ks*64 + lg*16);
#pragma unroll
      for (int fd = 0; fd < 8; ++fd) {
        int row = fd*16 + lr;
        bf16x8 vf = *(const bf16x8*)((const char*)lV + row*128 + ((ks*64 + lg*16) ^ ((row & 7) << 4)));
        oacc[fd] = __builtin_amdgcn_mfma_f32_16x16x32_bf16(pf, vf, oacc[fd], 0, 0, 0);
      }
    }
    __builtin_amdgcn_s_setprio(0);
    asm volatile("" ::: "memory");
    __builtin_amdgcn_s_barrier();
    asm volatile("" ::: "memory");
    if (kt < nt-1) STAGE_V(kt + 1);
    cur ^= 1;
  }
#undef STAGE_K
#undef STAGE_V
  // epilogue
  float invl[4];
#pragma unroll
  for (int j = 0; j < 4; ++j) invl[j] = 1.0f / ls[j];
#pragma unroll
  for (int fd = 0; fd < 8; ++fd)
#pragma unroll
    for (int j = 0; j < 4; ++j) {
      int qq = qt*128 + w*16 + lg*4 + j;
      int dd = fd*16 + lr;
      float v = oacc[fd][j] * invl[j];
      AO[((size_t)b*S_ + qq)*D_ + h*HD_ + dd] = f2bf(v);
    }
}

// ---------------- launch ----------------
extern "C" void kernel_launch(void* const* d_in, const int* in_sizes, int n_in,
                              void* d_out, int out_size, void* d_ws, size_t ws_size,
                              hipStream_t stream) {
  const float* x        = (const float*)d_in[0];
  const float* w_qkv    = (const float*)d_in[1];
  const float* w_out    = (const float*)d_in[2];
  const float* attn_sc  = (const float*)d_in[3];
  const float* freqs    = (const float*)d_in[4];

  if (ws_size < 167772160u) return;  // need 160 MB scratch

  char* ws = (char*)d_ws;
  u16* xbf  = (u16*)(ws);                 //  16 MB  [4096][2048]
  u16* wqbf = (u16*)(ws + 16777216);      //  24 MB  [6144][2048]
  u16* wobf = (u16*)(ws + 41943040);      //   8 MB  [2048][2048]
  u16* qkv  = (u16*)(ws + 50331648);      //  48 MB  [4096][6144]
  u16* Qh   = (u16*)(ws + 100663296);     //  16 MB  [B*H][S][HD]
  u16* Kh   = (u16*)(ws + 117440512);     //  16 MB  [B*H][S][HD]
  u16* Vt   = (u16*)(ws + 134217728);     //  16 MB  [B*H][HD][S]
  u16* AO   = (u16*)(ws + 150994944);     //  16 MB  [4096][2048]

  castk<<<4096, 256, 0, stream>>>(x,     xbf,  8388608);
  castk<<<6144, 256, 0, stream>>>(w_qkv, wqbf, 12582912);
  castk<<<2048, 256, 0, stream>>>(w_out, wobf, 4194304);

  // QKV: 256x256 tiles -> (24, 16) = 384 blocks
  gemm8<1><<<dim3(24, 16), 512, 0, stream>>>(xbf, wqbf, qkv, 4096, 6144, 2048);

  rope_norm<<<16384, 256, 0, stream>>>(qkv, freqs, attn_sc, Qh, Kh);
  v_trans<<<1024, 256, 0, stream>>>(qkv, Vt);

  flash_attn<<<512, 512, 0, stream>>>(Qh, Kh, Vt, AO);

  // out-projection: 128x128 tiles, full-chip grid (16, 32) = 512 blocks
  gemm_bt<0><<<dim3(16, 32), 256, 0, stream>>>(AO, wobf, (float*)d_out, 4096, 2048, 2048);
}

// Round 8
// 297.886 us; speedup vs baseline: 1.1261x; 1.0400x over previous
//
#include <hip/hip_runtime.h>
#include <stdint.h>

#define B_  2
#define S_  2048
#define D_  2048
#define H_  16
#define HD_ 128
#define D3_ 6144

typedef unsigned short u16;
typedef __attribute__((ext_vector_type(8))) __bf16 bf16x8;
typedef __attribute__((ext_vector_type(4))) float f32x4;
typedef __attribute__((ext_vector_type(8))) u16  u16x8;
typedef __attribute__((ext_vector_type(2))) u16  u16x2;

__device__ inline u16 f2bf(float f) {
  union { float f; uint32_t u; } v; v.f = f;
  uint32_t r = v.u + 0x7FFFu + ((v.u >> 16) & 1u);
  return (u16)(r >> 16);
}
__device__ inline float bf2f(u16 u) {
  union { float f; uint32_t u; } v; v.u = ((uint32_t)u) << 16;
  return v.f;
}
__device__ inline void gload_lds16(const void* g, void* l) {
  __builtin_amdgcn_global_load_lds((const __attribute__((address_space(1))) uint32_t*)g,
                                   (__attribute__((address_space(3))) uint32_t*)l, 16, 0, 0);
}

// tile-boundary sync: all own ds_reads done (data in regs), all own staged
// gloads landed, then barrier. ONE of these per K-tile; no interior barriers.
#define TILE_SYNC() do { \
    asm volatile("s_waitcnt lgkmcnt(0)" ::: "memory"); \
    asm volatile("s_waitcnt vmcnt(0)" ::: "memory"); \
    __builtin_amdgcn_s_barrier(); \
    asm volatile("" ::: "memory"); \
  } while (0)

// ---------------- fp32 -> bf16 cast ----------------
__global__ __launch_bounds__(256) void castk(const float* __restrict__ in, u16* __restrict__ out, int n) {
  int i = blockIdx.x * 256 + threadIdx.x;
  int n8 = n >> 3;
  if (i < n8) {
    f32x4 a = ((const f32x4*)in)[2*i];
    f32x4 b = ((const f32x4*)in)[2*i + 1];
    u16x8 o;
#pragma unroll
    for (int j = 0; j < 4; ++j) o[j] = f2bf(a[j]);
#pragma unroll
    for (int j = 0; j < 4; ++j) o[4+j] = f2bf(b[j]);
    ((u16x8*)out)[i] = o;
  }
}

// ============ B^T GEMM, BM=BN=256, BK=64, 8 waves (2M x 4N, wave 128x64).
// LDS 128KB double-buffered. ONE barrier per K-tile; interior is straight-line
// {stage T+1 -> 24 ds_read_b128 -> 64 MFMA} with compiler-scheduled lgkm waits,
// so reads overlap MFMA. Staging only ever writes the inactive buffer. ============
template<int BF16OUT>
__global__ __launch_bounds__(512, 2) void gemm8(const u16* __restrict__ A, const u16* __restrict__ Bw,
                                                void* __restrict__ Cp, int M, int N, int K) {
  __shared__ __align__(16) u16 lds_[65536];   // 128 KB: A[2][32KB] | B[2][32KB]
  char* ldsb = (char*)lds_;
  const int tid = threadIdx.x;
  const int w = tid >> 6, l = tid & 63;
  const int lr = l & 15, lg = l >> 4;
  const int wr = w >> 2, wc = w & 3;          // 2 x 4 waves
  const int nbn = (int)gridDim.x;
  const int nwg = nbn * (int)gridDim.y;
  const int bid = (int)(blockIdx.y * gridDim.x + blockIdx.x);
  const int swz = (bid & 7) * (nwg >> 3) + (bid >> 3);   // XCD swizzle (nwg%8==0)
  const int bm = swz / nbn, bn = swz % nbn;

  f32x4 acc[8][4] = {};

  // staging map: tile = 256 rows x 64 cols bf16 = 32KB = 4 chunks of 8KB
  int row4[4], col4[4];
#pragma unroll
  for (int i = 0; i < 4; ++i) {
    int off = i*8192 + tid*16;
    row4[i] = off >> 7;                              // 0..255
    col4[i] = (off & 127) ^ ((row4[i] & 7) << 4);    // involution source swizzle
  }
  const size_t rs = (size_t)K * 2;
  const char* Ab = (const char*)A + (size_t)bm * 256 * rs;
  const char* Bb = (const char*)Bw + (size_t)bn * 256 * rs;
  const int wb = w * 1024;

#define STG(T_) do { \
    char* dA_ = ldsb + ((T_)&1)*32768; \
    char* dB_ = ldsb + 65536 + ((T_)&1)*32768; \
    _Pragma("unroll") \
    for (int i_ = 0; i_ < 4; ++i_) \
      gload_lds16(Ab + (size_t)row4[i_]*rs + (size_t)(T_)*128 + col4[i_], dA_ + i_*8192 + wb); \
    _Pragma("unroll") \
    for (int i_ = 0; i_ < 4; ++i_) \
      gload_lds16(Bb + (size_t)row4[i_]*rs + (size_t)(T_)*128 + col4[i_], dB_ + i_*8192 + wb); \
  } while (0)

#define RD_A(dst, mf, ks) do { int row_ = wr*128 + (mf)*16 + lr; \
    dst = *(const bf16x8*)(La + row_*128 + (((ks)*64 + lg*16) ^ ((row_ & 7) << 4))); } while (0)
#define RD_B(dst, nf, ks) do { int row_ = wc*64 + (nf)*16 + lr; \
    dst = *(const bf16x8*)(Lb + row_*128 + (((ks)*64 + lg*16) ^ ((row_ & 7) << 4))); } while (0)

  const int NT = K >> 6;
  STG(0);
  TILE_SYNC();

  for (int T = 0; T < NT; ++T) {
    const char* La = ldsb + (T & 1)*32768;
    const char* Lb = ldsb + 65536 + (T & 1)*32768;
    if (T + 1 < NT) STG(T + 1);          // 8 gloads into the inactive buffer

    bf16x8 a0[4], a1[4], b0[4], b1[4];
    // half 0: mf 0-3 (16 reads -> 32 MFMA; compiler pipelines lgkm waits)
#pragma unroll
    for (int mf = 0; mf < 4; ++mf) { RD_A(a0[mf], mf, 0); RD_A(a1[mf], mf, 1); }
#pragma unroll
    for (int nf = 0; nf < 4; ++nf) { RD_B(b0[nf], nf, 0); RD_B(b1[nf], nf, 1); }
#pragma unroll
    for (int mf = 0; mf < 4; ++mf)
#pragma unroll
      for (int nf = 0; nf < 4; ++nf) {
        acc[mf][nf] = __builtin_amdgcn_mfma_f32_16x16x32_bf16(a0[mf], b0[nf], acc[mf][nf], 0, 0, 0);
        acc[mf][nf] = __builtin_amdgcn_mfma_f32_16x16x32_bf16(a1[mf], b1[nf], acc[mf][nf], 0, 0, 0);
      }
    // half 1: mf 4-7 (8 reads -> 32 MFMA; B frags reused from regs)
#pragma unroll
    for (int mf = 0; mf < 4; ++mf) { RD_A(a0[mf], mf + 4, 0); RD_A(a1[mf], mf + 4, 1); }
#pragma unroll
    for (int mf = 0; mf < 4; ++mf)
#pragma unroll
      for (int nf = 0; nf < 4; ++nf) {
        acc[mf+4][nf] = __builtin_amdgcn_mfma_f32_16x16x32_bf16(a0[mf], b0[nf], acc[mf+4][nf], 0, 0, 0);
        acc[mf+4][nf] = __builtin_amdgcn_mfma_f32_16x16x32_bf16(a1[mf], b1[nf], acc[mf+4][nf], 0, 0, 0);
      }
    TILE_SYNC();   // own reads consumed + tile T+1 landed + all waves arrived
  }
#undef STG
#undef RD_A
#undef RD_B

#pragma unroll
  for (int mf = 0; mf < 8; ++mf)
#pragma unroll
    for (int nf = 0; nf < 4; ++nf)
#pragma unroll
      for (int j = 0; j < 4; ++j) {
        int m = bm*256 + wr*128 + mf*16 + lg*4 + j;
        int n = bn*256 + wc*64 + nf*16 + lr;
        float v = acc[mf][nf][j];
        if (BF16OUT) ((u16*)Cp)[(size_t)m * N + n] = f2bf(v);
        else         ((float*)Cp)[(size_t)m * N + n] = v;
      }
}

// ---------------- 128x128 B^T GEMM, BK=64 double-buffered, 1 barrier/K-tile,
// LDS 64KB -> 2 blocks/CU (boundary stalls hide under co-resident block). ----------------
template<int BF16OUT>
__global__ __launch_bounds__(256, 2) void gemm_bt(const u16* __restrict__ A, const u16* __restrict__ Bw,
                                                  void* __restrict__ Cp, int M, int N, int K) {
  __shared__ __align__(16) u16 lds_[32768];   // 64 KB: A[2][16KB] | B[2][16KB]
  char* ldsb = (char*)lds_;
  const int tid = threadIdx.x;
  const int w = tid >> 6, l = tid & 63;
  const int lr = l & 15, lg = l >> 4;
  const int nwg = (int)(gridDim.x * gridDim.y);
  const int bid = (int)(blockIdx.y * gridDim.x + blockIdx.x);
  const int swz = (bid & 7) * (nwg >> 3) + (bid >> 3);
  const int bm = swz / (int)gridDim.x, bn = swz % (int)gridDim.x;
  const int wr = w >> 1, wc = w & 1;

  f32x4 acc[4][4] = {};

  // staging map: tile = 128 rows x 64 cols = 16KB = 4 chunks of 4KB
  int row4[4], col4[4];
#pragma unroll
  for (int i = 0; i < 4; ++i) {
    int off = i*4096 + tid*16;
    row4[i] = off >> 7;                              // 0..127
    col4[i] = (off & 127) ^ ((row4[i] & 7) << 4);
  }
  const size_t rs = (size_t)K * 2;
  const char* Ab = (const char*)A + (size_t)bm * 128 * rs;
  const char* Bb = (const char*)Bw + (size_t)bn * 128 * rs;
  const int wb = w * 1024;

#define STG(T_) do { \
    char* dA_ = ldsb + ((T_)&1)*16384; \
    char* dB_ = ldsb + 32768 + ((T_)&1)*16384; \
    _Pragma("unroll") \
    for (int i_ = 0; i_ < 4; ++i_) \
      gload_lds16(Ab + (size_t)row4[i_]*rs + (size_t)(T_)*128 + col4[i_], dA_ + i_*4096 + wb); \
    _Pragma("unroll") \
    for (int i_ = 0; i_ < 4; ++i_) \
      gload_lds16(Bb + (size_t)row4[i_]*rs + (size_t)(T_)*128 + col4[i_], dB_ + i_*4096 + wb); \
  } while (0)

  const int NT = K >> 6;
  STG(0);
  TILE_SYNC();

  for (int T = 0; T < NT; ++T) {
    const char* La = ldsb + (T & 1)*16384;
    const char* Lb = ldsb + 32768 + (T & 1)*16384;
    if (T + 1 < NT) STG(T + 1);

    bf16x8 af[4][2], bf[4][2];
#pragma unroll
    for (int mt = 0; mt < 4; ++mt) {
      int row = wr*64 + mt*16 + lr;
#pragma unroll
      for (int ks = 0; ks < 2; ++ks)
        af[mt][ks] = *(const bf16x8*)(La + row*128 + ((ks*64 + lg*16) ^ ((row & 7) << 4)));
    }
#pragma unroll
    for (int nt = 0; nt < 4; ++nt) {
      int row = wc*64 + nt*16 + lr;
#pragma unroll
      for (int ks = 0; ks < 2; ++ks)
        bf[nt][ks] = *(const bf16x8*)(Lb + row*128 + ((ks*64 + lg*16) ^ ((row & 7) << 4)));
    }
#pragma unroll
    for (int mt = 0; mt < 4; ++mt)
#pragma unroll
      for (int nt = 0; nt < 4; ++nt)
#pragma unroll
        for (int ks = 0; ks < 2; ++ks)
          acc[mt][nt] = __builtin_amdgcn_mfma_f32_16x16x32_bf16(af[mt][ks], bf[nt][ks], acc[mt][nt], 0, 0, 0);
    TILE_SYNC();
  }
#undef STG

#pragma unroll
  for (int mt = 0; mt < 4; ++mt)
#pragma unroll
    for (int nt = 0; nt < 4; ++nt)
#pragma unroll
      for (int j = 0; j < 4; ++j) {
        int m = bm*128 + wr*64 + mt*16 + lg*4 + j;
        int n = bn*128 + wc*64 + nt*16 + lr;
        float v = acc[mt][nt][j];
        if (BF16OUT) ((u16*)Cp)[(size_t)m * N + n] = f2bf(v);
        else         ((float*)Cp)[(size_t)m * N + n] = v;
      }
}

// ---------------- RoPE + per-head L2 norm (+attn_scale*log2e on Q) ----------------
__global__ __launch_bounds__(256) void rope_norm(const u16* __restrict__ qkv, const float* __restrict__ fc,
                                                 const float* __restrict__ scale_p,
                                                 u16* __restrict__ Qo, u16* __restrict__ Ko) {
  int gid = blockIdx.x;
  int bs = gid >> 2;
  int s = bs & (S_ - 1);
  int b = bs >> 11;
  int w = threadIdx.x >> 6, l = threadIdx.x & 63;
  int h = (gid & 3)*4 + w;
  float2 cs = ((const float2*)fc)[(size_t)s*64 + l];
  float scale = scale_p[0] * 1.4426950408889634f;  // fold log2(e) for exp2 softmax
  const u16* base = qkv + (size_t)bs * D3_;
  size_t obase = ((size_t)(b*H_ + h) * S_ + s) * HD_ + 2*l;
  {
    const u16* p = base + h*HD_ + 2*l;
    float x0 = bf2f(p[0]), x1 = bf2f(p[1]);
    float r0 = x0*cs.x - x1*cs.y;
    float r1 = x1*cs.x + x0*cs.y;
    float t = r0*r0 + r1*r1;
#pragma unroll
    for (int mk = 1; mk < 64; mk <<= 1) t += __shfl_xor(t, mk, 64);
    float inv = scale / (sqrtf(t) + 1e-6f);
    u16x2 o; o[0] = f2bf(r0*inv); o[1] = f2bf(r1*inv);
    *(u16x2*)(Qo + obase) = o;
  }
  {
    const u16* p = base + D_ + h*HD_ + 2*l;
    float x0 = bf2f(p[0]), x1 = bf2f(p[1]);
    float r0 = x0*cs.x - x1*cs.y;
    float r1 = x1*cs.x + x0*cs.y;
    float t = r0*r0 + r1*r1;
#pragma unroll
    for (int mk = 1; mk < 64; mk <<= 1) t += __shfl_xor(t, mk, 64);
    float inv = 1.0f / (sqrtf(t) + 1e-6f);
    u16x2 o; o[0] = f2bf(r0*inv); o[1] = f2bf(r1*inv);
    *(u16x2*)(Ko + obase) = o;
  }
}

// ---------------- V transpose: qkv v-slice [B,S,H,HD] -> Vt [B*H, HD, S] ----------------
__global__ __launch_bounds__(256) void v_trans(const u16* __restrict__ qkv, u16* __restrict__ Vt) {
  __shared__ u16 vt[64][136];
  int blk = blockIdx.x;
  int bh = blk >> 5, st = blk & 31;
  int b = bh >> 4, h = bh & 15;
  int s0 = st * 64;
  int tid = threadIdx.x;
#pragma unroll
  for (int i = 0; i < 4; ++i) {
    int idx = tid + i*256;
    int row = idx >> 4, ch = idx & 15;
    u16x8 v = *(const u16x8*)(qkv + (size_t)(b*S_ + s0 + row) * D3_ + 2*D_ + h*HD_ + ch*8);
    *(u16x8*)(&vt[row][ch*8]) = v;
  }
  __syncthreads();
#pragma unroll
  for (int p = 0; p < 2; ++p) {
    int d = p*64 + (tid >> 2);
    int q = (tid & 3) * 16;
    u16x8 t0, t1;
#pragma unroll
    for (int i = 0; i < 8; ++i) t0[i] = vt[q + i][d];
#pragma unroll
    for (int i = 0; i < 8; ++i) t1[i] = vt[q + 8 + i][d];
    u16* dst = Vt + ((size_t)bh * HD_ + d) * S_ + s0 + q;
    *(u16x8*)dst = t0;
    *(u16x8*)(dst + 8) = t1;
  }
}

// ---------------- causal flash attention ----------------
// QBLK=128, 8 waves (512 thr), KBLK=64. K double-buffered, V single-buffered.
// Counted vmcnt, never 0 except last tile. setprio around MFMA clusters (T5).
__global__ __launch_bounds__(512) void flash_attn(const u16* __restrict__ Qh, const u16* __restrict__ Kh,
                                                  const u16* __restrict__ Vt, u16* __restrict__ AO) {
  __shared__ __align__(16) u16 lK[2][64*128];   // 32 KB
  __shared__ __align__(16) u16 lV[128*64];      // 16 KB
  __shared__ __align__(16) u16 lP[8][16*72];    // 18 KB
  const int i0 = (int)blockIdx.x;               // 0..511
  const int k5 = i0 & 255;
  const int bh = k5 >> 3;
  const int jj = k5 & 7;
  const int qt = (i0 < 256) ? (15 - jj) : jj;   // heavy half first
  const int tid = threadIdx.x, w = tid >> 6, l = tid & 63;
  const int lr = l & 15, lg = l >> 4;
  const int b = bh >> 4, h = bh & 15;

  bf16x8 qf[4];
  {
    const u16* qp = Qh + ((size_t)bh * S_ + qt*128 + w*16 + lr) * HD_ + lg*8;
#pragma unroll
    for (int ks = 0; ks < 4; ++ks) qf[ks] = *(const bf16x8*)(qp + ks*32);
  }
  float m[4], ls[4];
  f32x4 oacc[8] = {};
#pragma unroll
  for (int j = 0; j < 4; ++j) { m[j] = -__builtin_inff(); ls[j] = 0.f; }

  int krow[2], kcol[2], vrow[2], vcol[2], dstb[2];
#pragma unroll
  for (int p = 0; p < 2; ++p) {
    int off = p*8192 + tid*16;
    krow[p] = off >> 8; kcol[p] = (off & 255) ^ ((krow[p] & 7) << 4);
    vrow[p] = off >> 7; vcol[p] = (off & 127) ^ ((vrow[p] & 7) << 4);
    dstb[p] = p*8192 + w*1024;
  }
  const char* Kb = (const char*)(Kh + (size_t)bh * S_ * HD_);
  const char* Vb = (const char*)(Vt + (size_t)bh * HD_ * S_);

#define STAGE_K(nb, kt_) do {                                                       \
    _Pragma("unroll")                                                               \
    for (int p_ = 0; p_ < 2; ++p_)                                                  \
      gload_lds16(Kb + (size_t)((kt_)*64 + krow[p_])*256 + kcol[p_],                \
                  (char*)lK[nb] + dstb[p_]);                                        \
  } while (0)
#define STAGE_V(kt_) do {                                                           \
    _Pragma("unroll")                                                               \
    for (int p_ = 0; p_ < 2; ++p_)                                                  \
      gload_lds16(Vb + (size_t)vrow[p_]*(S_*2) + (kt_)*128 + vcol[p_],              \
                  (char*)lV + dstb[p_]);                                            \
  } while (0)

  const int nt = 2*qt + 2;
  STAGE_K(0, 0);
  STAGE_V(0);
  int cur = 0;
  for (int kt = 0; kt < nt; ++kt) {
    asm volatile("s_waitcnt vmcnt(2)" ::: "memory");
    __builtin_amdgcn_s_barrier();
    asm volatile("" ::: "memory");
    const char* lKb = (const char*)lK[cur];

    // QK^T
    f32x4 sc[4] = {};
    __builtin_amdgcn_s_setprio(1);
#pragma unroll
    for (int f = 0; f < 4; ++f) {
      int row = f*16 + lr;
#pragma unroll
      for (int ks = 0; ks < 4; ++ks) {
        bf16x8 kf = *(const bf16x8*)(lKb + row*256 + ((ks*64 + lg*16) ^ ((row & 7) << 4)));
        sc[f] = __builtin_amdgcn_mfma_f32_16x16x32_bf16(qf[ks], kf, sc[f], 0, 0, 0);
      }
    }
    __builtin_amdgcn_s_setprio(0);
    if (kt < nt-1) STAGE_K(cur ^ 1, kt + 1);   // prefetch next K under softmax

    if (kt >= nt-2) {  // diagonal tiles only
#pragma unroll
      for (int f = 0; f < 4; ++f)
#pragma unroll
        for (int j = 0; j < 4; ++j)
          if (kt*64 + f*16 + lr > qt*128 + w*16 + lg*4 + j) sc[f][j] = -__builtin_inff();
    }
    // online softmax (base-2; log2e folded into Q)
    float rm[4], resc[4], rowp[4];
#pragma unroll
    for (int j = 0; j < 4; ++j) {
      rm[j] = fmaxf(fmaxf(sc[0][j], sc[1][j]), fmaxf(sc[2][j], sc[3][j]));
      rm[j] = fmaxf(rm[j], __shfl_xor(rm[j], 1, 64));
      rm[j] = fmaxf(rm[j], __shfl_xor(rm[j], 2, 64));
      rm[j] = fmaxf(rm[j], __shfl_xor(rm[j], 4, 64));
      rm[j] = fmaxf(rm[j], __shfl_xor(rm[j], 8, 64));
      float mn = fmaxf(m[j], rm[j]);
      resc[j] = exp2f(m[j] - mn);
      m[j] = mn;
      rowp[j] = 0.f;
    }
#pragma unroll
    for (int f = 0; f < 4; ++f)
#pragma unroll
      for (int j = 0; j < 4; ++j) {
        float p = exp2f(sc[f][j] - m[j]);
        sc[f][j] = p;
        rowp[j] += p;
      }
#pragma unroll
    for (int j = 0; j < 4; ++j) {
      rowp[j] += __shfl_xor(rowp[j], 1, 64);
      rowp[j] += __shfl_xor(rowp[j], 2, 64);
      rowp[j] += __shfl_xor(rowp[j], 4, 64);
      rowp[j] += __shfl_xor(rowp[j], 8, 64);
      ls[j] = ls[j] * resc[j] + rowp[j];
    }
#pragma unroll
    for (int fd = 0; fd < 8; ++fd)
#pragma unroll
      for (int j = 0; j < 4; ++j) oacc[fd][j] *= resc[j];
    // P -> wave-private LDS
#pragma unroll
    for (int f = 0; f < 4; ++f)
#pragma unroll
      for (int j = 0; j < 4; ++j)
        lP[w][(lg*4 + j)*72 + f*16 + lr] = f2bf(sc[f][j]);

    if (kt < nt-1) { asm volatile("s_waitcnt vmcnt(2)" ::: "memory"); }
    else           { asm volatile("s_waitcnt vmcnt(0)" ::: "memory"); }
    __builtin_amdgcn_s_barrier();
    asm volatile("" ::: "memory");
    // PV
    __builtin_amdgcn_s_setprio(1);
#pragma unroll
    for (int ks = 0; ks < 2; ++ks) {
      bf16x8 pf = *(const bf16x8*)((const char*)lP[w] + lr*144 + ks*64 + lg*16);
#pragma unroll
      for (int fd = 0; fd < 8; ++fd) {
        int row = fd*16 + lr;
        bf16x8 vf = *(const bf16x8*)((const char*)lV + row*128 + ((ks*64 + lg*16) ^ ((row & 7) << 4)));
        oacc[fd] = __builtin_amdgcn_mfma_f32_16x16x32_bf16(pf, vf, oacc[fd], 0, 0, 0);
      }
    }
    __builtin_amdgcn_s_setprio(0);
    asm volatile("" ::: "memory");
    __builtin_amdgcn_s_barrier();
    asm volatile("" ::: "memory");
    if (kt < nt-1) STAGE_V(kt + 1);
    cur ^= 1;
  }
#undef STAGE_K
#undef STAGE_V
  // epilogue
  float invl[4];
#pragma unroll
  for (int j = 0; j < 4; ++j) invl[j] = 1.0f / ls[j];
#pragma unroll
  for (int fd = 0; fd < 8; ++fd)
#pragma unroll
    for (int j = 0; j < 4; ++j) {
      int qq = qt*128 + w*16 + lg*4 + j;
      int dd = fd*16 + lr;
      float v = oacc[fd][j] * invl[j];
      AO[((size_t)b*S_ + qq)*D_ + h*HD_ + dd] = f2bf(v);
    }
}

// ---------------- launch ----------------
extern "C" void kernel_launch(void* const* d_in, const int* in_sizes, int n_in,
                              void* d_out, int out_size, void* d_ws, size_t ws_size,
                              hipStream_t stream) {
  const float* x        = (const float*)d_in[0];
  const float* w_qkv    = (const float*)d_in[1];
  const float* w_out    = (const float*)d_in[2];
  const float* attn_sc  = (const float*)d_in[3];
  const float* freqs    = (const float*)d_in[4];

  if (ws_size < 167772160u) return;  // need 160 MB scratch

  char* ws = (char*)d_ws;
  u16* xbf  = (u16*)(ws);                 //  16 MB  [4096][2048]
  u16* wqbf = (u16*)(ws + 16777216);      //  24 MB  [6144][2048]
  u16* wobf = (u16*)(ws + 41943040);      //   8 MB  [2048][2048]
  u16* qkv  = (u16*)(ws + 50331648);      //  48 MB  [4096][6144]
  u16* Qh   = (u16*)(ws + 100663296);     //  16 MB  [B*H][S][HD]
  u16* Kh   = (u16*)(ws + 117440512);     //  16 MB  [B*H][S][HD]
  u16* Vt   = (u16*)(ws + 134217728);     //  16 MB  [B*H][HD][S]
  u16* AO   = (u16*)(ws + 150994944);     //  16 MB  [4096][2048]

  castk<<<4096, 256, 0, stream>>>(x,     xbf,  8388608);
  castk<<<6144, 256, 0, stream>>>(w_qkv, wqbf, 12582912);
  castk<<<2048, 256, 0, stream>>>(w_out, wobf, 4194304);

  // QKV: 256x256 tiles -> (24, 16) = 384 blocks
  gemm8<1><<<dim3(24, 16), 512, 0, stream>>>(xbf, wqbf, qkv, 4096, 6144, 2048);

  rope_norm<<<16384, 256, 0, stream>>>(qkv, freqs, attn_sc, Qh, Kh);
  v_trans<<<1024, 256, 0, stream>>>(qkv, Vt);

  flash_attn<<<512, 512, 0, stream>>>(Qh, Kh, Vt, AO);

  // out-projection: 128x128 tiles, (16, 32) = 512 blocks, 2 blocks/CU
  gemm_bt<0><<<dim3(16, 32), 256, 0, stream>>>(AO, wobf, (float*)d_out, 4096, 2048, 2048);
}

// Round 9
// 293.861 us; speedup vs baseline: 1.1415x; 1.0137x over previous
//
#include <hip/hip_runtime.h>
#include <stdint.h>

#define B_  2
#define S_  2048
#define D_  2048
#define H_  16
#define HD_ 128
#define D3_ 6144

typedef unsigned short u16;
typedef __attribute__((ext_vector_type(8))) __bf16 bf16x8;
typedef __attribute__((ext_vector_type(4))) float f32x4;
typedef __attribute__((ext_vector_type(8))) u16  u16x8;
typedef __attribute__((ext_vector_type(2))) u16  u16x2;

__device__ inline u16 f2bf(float f) {
  union { float f; uint32_t u; } v; v.f = f;
  uint32_t r = v.u + 0x7FFFu + ((v.u >> 16) & 1u);
  return (u16)(r >> 16);
}
__device__ inline float bf2f(u16 u) {
  union { float f; uint32_t u; } v; v.u = ((uint32_t)u) << 16;
  return v.f;
}
__device__ inline void gload_lds16(const void* g, void* l) {
  __builtin_amdgcn_global_load_lds((const __attribute__((address_space(1))) uint32_t*)g,
                                   (__attribute__((address_space(3))) uint32_t*)l, 16, 0, 0);
}

// tile-boundary sync: own ds_reads consumed, own staged gloads landed, barrier.
#define TILE_SYNC() do { \
    asm volatile("s_waitcnt lgkmcnt(0)" ::: "memory"); \
    asm volatile("s_waitcnt vmcnt(0)" ::: "memory"); \
    __builtin_amdgcn_s_barrier(); \
    asm volatile("" ::: "memory"); \
  } while (0)

// ---------------- fp32 -> bf16 cast ----------------
__global__ __launch_bounds__(256) void castk(const float* __restrict__ in, u16* __restrict__ out, int n) {
  int i = blockIdx.x * 256 + threadIdx.x;
  int n8 = n >> 3;
  if (i < n8) {
    f32x4 a = ((const f32x4*)in)[2*i];
    f32x4 b = ((const f32x4*)in)[2*i + 1];
    u16x8 o;
#pragma unroll
    for (int j = 0; j < 4; ++j) o[j] = f2bf(a[j]);
#pragma unroll
    for (int j = 0; j < 4; ++j) o[4+j] = f2bf(b[j]);
    ((u16x8*)out)[i] = o;
  }
}

// ============ B^T GEMM, BM=256, BN=128, BK=64, 8 waves (4M x 2N, wave 64x64).
// Grid = exact multiple of 256 CUs. LDS 96KB double-buffered. ONE barrier per
// K-tile, straight-line interior; MFMAs in 2 ks-passes (dep distance 16). ============
template<int BF16OUT>
__global__ __launch_bounds__(512, 2) void gemm8(const u16* __restrict__ A, const u16* __restrict__ Bw,
                                                void* __restrict__ Cp, int M, int N, int K) {
  __shared__ __align__(16) u16 lds_[49152];   // 96 KB: A[2][32KB] | B[2][16KB]
  char* ldsb = (char*)lds_;
  const int tid = threadIdx.x;
  const int w = tid >> 6, l = tid & 63;
  const int lr = l & 15, lg = l >> 4;
  const int wr = w >> 1, wc = w & 1;          // 4M x 2N waves
  const int nbn = (int)gridDim.x;
  const int nwg = nbn * (int)gridDim.y;
  const int bid = (int)(blockIdx.y * gridDim.x + blockIdx.x);
  const int swz = (bid & 7) * (nwg >> 3) + (bid >> 3);   // XCD swizzle (nwg%8==0)
  const int bm = swz / nbn, bn = swz % nbn;

  f32x4 acc[4][4] = {};

  // staging maps (16B/lane, involution source swizzle within 128B rows)
  int rowA[4], colA[4], rowB[2], colB[2];
#pragma unroll
  for (int i = 0; i < 4; ++i) {
    int off = i*8192 + tid*16;
    rowA[i] = off >> 7;                              // 0..255
    colA[i] = (off & 127) ^ ((rowA[i] & 7) << 4);
  }
#pragma unroll
  for (int i = 0; i < 2; ++i) {
    int off = i*8192 + tid*16;
    rowB[i] = off >> 7;                              // 0..127
    colB[i] = (off & 127) ^ ((rowB[i] & 7) << 4);
  }
  const size_t rs = (size_t)K * 2;
  const char* Ab = (const char*)A + (size_t)bm * 256 * rs;
  const char* Bb = (const char*)Bw + (size_t)bn * 128 * rs;
  const int wb = w * 1024;

#define STG(T_) do { \
    char* dA_ = ldsb + ((T_)&1)*32768; \
    char* dB_ = ldsb + 65536 + ((T_)&1)*16384; \
    _Pragma("unroll") \
    for (int i_ = 0; i_ < 4; ++i_) \
      gload_lds16(Ab + (size_t)rowA[i_]*rs + (size_t)(T_)*128 + colA[i_], dA_ + i_*8192 + wb); \
    _Pragma("unroll") \
    for (int i_ = 0; i_ < 2; ++i_) \
      gload_lds16(Bb + (size_t)rowB[i_]*rs + (size_t)(T_)*128 + colB[i_], dB_ + i_*8192 + wb); \
  } while (0)

  const int NT = K >> 6;
  STG(0);
  TILE_SYNC();

  for (int T = 0; T < NT; ++T) {
    const char* La = ldsb + (T & 1)*32768;
    const char* Lb = ldsb + 65536 + (T & 1)*16384;
    if (T + 1 < NT) STG(T + 1);          // 6 gloads into the inactive buffer

    bf16x8 a0[4], a1[4], b0[4], b1[4];
#pragma unroll
    for (int mf = 0; mf < 4; ++mf) {
      int row = wr*64 + mf*16 + lr;
      a0[mf] = *(const bf16x8*)(La + row*128 + ((lg*16)      ^ ((row & 7) << 4)));
      a1[mf] = *(const bf16x8*)(La + row*128 + ((64 + lg*16) ^ ((row & 7) << 4)));
    }
#pragma unroll
    for (int nf = 0; nf < 4; ++nf) {
      int row = wc*64 + nf*16 + lr;
      b0[nf] = *(const bf16x8*)(Lb + row*128 + ((lg*16)      ^ ((row & 7) << 4)));
      b1[nf] = *(const bf16x8*)(Lb + row*128 + ((64 + lg*16) ^ ((row & 7) << 4)));
    }
    // pass ks0: 16 independent MFMAs; pass ks1: dependent reuse at distance 16
#pragma unroll
    for (int mf = 0; mf < 4; ++mf)
#pragma unroll
      for (int nf = 0; nf < 4; ++nf)
        acc[mf][nf] = __builtin_amdgcn_mfma_f32_16x16x32_bf16(a0[mf], b0[nf], acc[mf][nf], 0, 0, 0);
#pragma unroll
    for (int mf = 0; mf < 4; ++mf)
#pragma unroll
      for (int nf = 0; nf < 4; ++nf)
        acc[mf][nf] = __builtin_amdgcn_mfma_f32_16x16x32_bf16(a1[mf], b1[nf], acc[mf][nf], 0, 0, 0);
    TILE_SYNC();
  }
#undef STG

#pragma unroll
  for (int mf = 0; mf < 4; ++mf)
#pragma unroll
    for (int nf = 0; nf < 4; ++nf)
#pragma unroll
      for (int j = 0; j < 4; ++j) {
        int m = bm*256 + wr*64 + mf*16 + lg*4 + j;
        int n = bn*128 + wc*64 + nf*16 + lr;
        float v = acc[mf][nf][j];
        if (BF16OUT) ((u16*)Cp)[(size_t)m * N + n] = f2bf(v);
        else         ((float*)Cp)[(size_t)m * N + n] = v;
      }
}

// ---------------- 128x128 B^T GEMM, BK=64 dbuf, 1 barrier/K-tile, 2 blocks/CU ----------------
template<int BF16OUT>
__global__ __launch_bounds__(256, 2) void gemm_bt(const u16* __restrict__ A, const u16* __restrict__ Bw,
                                                  void* __restrict__ Cp, int M, int N, int K) {
  __shared__ __align__(16) u16 lds_[32768];   // 64 KB: A[2][16KB] | B[2][16KB]
  char* ldsb = (char*)lds_;
  const int tid = threadIdx.x;
  const int w = tid >> 6, l = tid & 63;
  const int lr = l & 15, lg = l >> 4;
  const int nwg = (int)(gridDim.x * gridDim.y);
  const int bid = (int)(blockIdx.y * gridDim.x + blockIdx.x);
  const int swz = (bid & 7) * (nwg >> 3) + (bid >> 3);
  const int bm = swz / (int)gridDim.x, bn = swz % (int)gridDim.x;
  const int wr = w >> 1, wc = w & 1;

  f32x4 acc[4][4] = {};

  int row4[4], col4[4];
#pragma unroll
  for (int i = 0; i < 4; ++i) {
    int off = i*4096 + tid*16;
    row4[i] = off >> 7;                              // 0..127
    col4[i] = (off & 127) ^ ((row4[i] & 7) << 4);
  }
  const size_t rs = (size_t)K * 2;
  const char* Ab = (const char*)A + (size_t)bm * 128 * rs;
  const char* Bb = (const char*)Bw + (size_t)bn * 128 * rs;
  const int wb = w * 1024;

#define STG(T_) do { \
    char* dA_ = ldsb + ((T_)&1)*16384; \
    char* dB_ = ldsb + 32768 + ((T_)&1)*16384; \
    _Pragma("unroll") \
    for (int i_ = 0; i_ < 4; ++i_) \
      gload_lds16(Ab + (size_t)row4[i_]*rs + (size_t)(T_)*128 + col4[i_], dA_ + i_*4096 + wb); \
    _Pragma("unroll") \
    for (int i_ = 0; i_ < 4; ++i_) \
      gload_lds16(Bb + (size_t)row4[i_]*rs + (size_t)(T_)*128 + col4[i_], dB_ + i_*4096 + wb); \
  } while (0)

  const int NT = K >> 6;
  STG(0);
  TILE_SYNC();

  for (int T = 0; T < NT; ++T) {
    const char* La = ldsb + (T & 1)*16384;
    const char* Lb = ldsb + 32768 + (T & 1)*16384;
    if (T + 1 < NT) STG(T + 1);

    bf16x8 af[4][2], bf[4][2];
#pragma unroll
    for (int mt = 0; mt < 4; ++mt) {
      int row = wr*64 + mt*16 + lr;
#pragma unroll
      for (int ks = 0; ks < 2; ++ks)
        af[mt][ks] = *(const bf16x8*)(La + row*128 + ((ks*64 + lg*16) ^ ((row & 7) << 4)));
    }
#pragma unroll
    for (int nt = 0; nt < 4; ++nt) {
      int row = wc*64 + nt*16 + lr;
#pragma unroll
      for (int ks = 0; ks < 2; ++ks)
        bf[nt][ks] = *(const bf16x8*)(Lb + row*128 + ((ks*64 + lg*16) ^ ((row & 7) << 4)));
    }
    // dep-split: all ks0 then all ks1
#pragma unroll
    for (int mt = 0; mt < 4; ++mt)
#pragma unroll
      for (int nt = 0; nt < 4; ++nt)
        acc[mt][nt] = __builtin_amdgcn_mfma_f32_16x16x32_bf16(af[mt][0], bf[nt][0], acc[mt][nt], 0, 0, 0);
#pragma unroll
    for (int mt = 0; mt < 4; ++mt)
#pragma unroll
      for (int nt = 0; nt < 4; ++nt)
        acc[mt][nt] = __builtin_amdgcn_mfma_f32_16x16x32_bf16(af[mt][1], bf[nt][1], acc[mt][nt], 0, 0, 0);
    TILE_SYNC();
  }
#undef STG

#pragma unroll
  for (int mt = 0; mt < 4; ++mt)
#pragma unroll
    for (int nt = 0; nt < 4; ++nt)
#pragma unroll
      for (int j = 0; j < 4; ++j) {
        int m = bm*128 + wr*64 + mt*16 + lg*4 + j;
        int n = bn*128 + wc*64 + nt*16 + lr;
        float v = acc[mt][nt][j];
        if (BF16OUT) ((u16*)Cp)[(size_t)m * N + n] = f2bf(v);
        else         ((float*)Cp)[(size_t)m * N + n] = v;
      }
}

// ---------------- RoPE + per-head L2 norm (+attn_scale*log2e on Q) ----------------
__global__ __launch_bounds__(256) void rope_norm(const u16* __restrict__ qkv, const float* __restrict__ fc,
                                                 const float* __restrict__ scale_p,
                                                 u16* __restrict__ Qo, u16* __restrict__ Ko) {
  int gid = blockIdx.x;
  int bs = gid >> 2;
  int s = bs & (S_ - 1);
  int b = bs >> 11;
  int w = threadIdx.x >> 6, l = threadIdx.x & 63;
  int h = (gid & 3)*4 + w;
  float2 cs = ((const float2*)fc)[(size_t)s*64 + l];
  float scale = scale_p[0] * 1.4426950408889634f;  // fold log2(e) for exp2 softmax
  const u16* base = qkv + (size_t)bs * D3_;
  size_t obase = ((size_t)(b*H_ + h) * S_ + s) * HD_ + 2*l;
  {
    const u16* p = base + h*HD_ + 2*l;
    float x0 = bf2f(p[0]), x1 = bf2f(p[1]);
    float r0 = x0*cs.x - x1*cs.y;
    float r1 = x1*cs.x + x0*cs.y;
    float t = r0*r0 + r1*r1;
#pragma unroll
    for (int mk = 1; mk < 64; mk <<= 1) t += __shfl_xor(t, mk, 64);
    float inv = scale / (sqrtf(t) + 1e-6f);
    u16x2 o; o[0] = f2bf(r0*inv); o[1] = f2bf(r1*inv);
    *(u16x2*)(Qo + obase) = o;
  }
  {
    const u16* p = base + D_ + h*HD_ + 2*l;
    float x0 = bf2f(p[0]), x1 = bf2f(p[1]);
    float r0 = x0*cs.x - x1*cs.y;
    float r1 = x1*cs.x + x0*cs.y;
    float t = r0*r0 + r1*r1;
#pragma unroll
    for (int mk = 1; mk < 64; mk <<= 1) t += __shfl_xor(t, mk, 64);
    float inv = 1.0f / (sqrtf(t) + 1e-6f);
    u16x2 o; o[0] = f2bf(r0*inv); o[1] = f2bf(r1*inv);
    *(u16x2*)(Ko + obase) = o;
  }
}

// ---------------- V transpose: qkv v-slice [B,S,H,HD] -> Vt [B*H, HD, S] ----------------
__global__ __launch_bounds__(256) void v_trans(const u16* __restrict__ qkv, u16* __restrict__ Vt) {
  __shared__ u16 vt[64][136];
  int blk = blockIdx.x;
  int bh = blk >> 5, st = blk & 31;
  int b = bh >> 4, h = bh & 15;
  int s0 = st * 64;
  int tid = threadIdx.x;
#pragma unroll
  for (int i = 0; i < 4; ++i) {
    int idx = tid + i*256;
    int row = idx >> 4, ch = idx & 15;
    u16x8 v = *(const u16x8*)(qkv + (size_t)(b*S_ + s0 + row) * D3_ + 2*D_ + h*HD_ + ch*8);
    *(u16x8*)(&vt[row][ch*8]) = v;
  }
  __syncthreads();
#pragma unroll
  for (int p = 0; p < 2; ++p) {
    int d = p*64 + (tid >> 2);
    int q = (tid & 3) * 16;
    u16x8 t0, t1;
#pragma unroll
    for (int i = 0; i < 8; ++i) t0[i] = vt[q + i][d];
#pragma unroll
    for (int i = 0; i < 8; ++i) t1[i] = vt[q + 8 + i][d];
    u16* dst = Vt + ((size_t)bh * HD_ + d) * S_ + s0 + q;
    *(u16x8*)dst = t0;
    *(u16x8*)(dst + 8) = t1;
  }
}

// ---------------- causal flash attention ----------------
// QBLK=128, 8 waves (512 thr), KBLK=64. K double-buffered, V single-buffered.
// Counted vmcnt, never 0 except last tile. setprio around MFMA clusters (T5).
__global__ __launch_bounds__(512) void flash_attn(const u16* __restrict__ Qh, const u16* __restrict__ Kh,
                                                  const u16* __restrict__ Vt, u16* __restrict__ AO) {
  __shared__ __align__(16) u16 lK[2][64*128];   // 32 KB
  __shared__ __align__(16) u16 lV[128*64];      // 16 KB
  __shared__ __align__(16) u16 lP[8][16*72];    // 18 KB
  const int i0 = (int)blockIdx.x;               // 0..511
  const int k5 = i0 & 255;
  const int bh = k5 >> 3;
  const int jj = k5 & 7;
  const int qt = (i0 < 256) ? (15 - jj) : jj;   // heavy half first
  const int tid = threadIdx.x, w = tid >> 6, l = tid & 63;
  const int lr = l & 15, lg = l >> 4;
  const int b = bh >> 4, h = bh & 15;

  bf16x8 qf[4];
  {
    const u16* qp = Qh + ((size_t)bh * S_ + qt*128 + w*16 + lr) * HD_ + lg*8;
#pragma unroll
    for (int ks = 0; ks < 4; ++ks) qf[ks] = *(const bf16x8*)(qp + ks*32);
  }
  float m[4], ls[4];
  f32x4 oacc[8] = {};
#pragma unroll
  for (int j = 0; j < 4; ++j) { m[j] = -__builtin_inff(); ls[j] = 0.f; }

  int krow[2], kcol[2], vrow[2], vcol[2], dstb[2];
#pragma unroll
  for (int p = 0; p < 2; ++p) {
    int off = p*8192 + tid*16;
    krow[p] = off >> 8; kcol[p] = (off & 255) ^ ((krow[p] & 7) << 4);
    vrow[p] = off >> 7; vcol[p] = (off & 127) ^ ((vrow[p] & 7) << 4);
    dstb[p] = p*8192 + w*1024;
  }
  const char* Kb = (const char*)(Kh + (size_t)bh * S_ * HD_);
  const char* Vb = (const char*)(Vt + (size_t)bh * HD_ * S_);

#define STAGE_K(nb, kt_) do {                                                       \
    _Pragma("unroll")                                                               \
    for (int p_ = 0; p_ < 2; ++p_)                                                  \
      gload_lds16(Kb + (size_t)((kt_)*64 + krow[p_])*256 + kcol[p_],                \
                  (char*)lK[nb] + dstb[p_]);                                        \
  } while (0)
#define STAGE_V(kt_) do {                                                           \
    _Pragma("unroll")                                                               \
    for (int p_ = 0; p_ < 2; ++p_)                                                  \
      gload_lds16(Vb + (size_t)vrow[p_]*(S_*2) + (kt_)*128 + vcol[p_],              \
                  (char*)lV + dstb[p_]);                                            \
  } while (0)

  const int nt = 2*qt + 2;
  STAGE_K(0, 0);
  STAGE_V(0);
  int cur = 0;
  for (int kt = 0; kt < nt; ++kt) {
    asm volatile("s_waitcnt vmcnt(2)" ::: "memory");
    __builtin_amdgcn_s_barrier();
    asm volatile("" ::: "memory");
    const char* lKb = (const char*)lK[cur];

    // QK^T (ks outer: dependent sc[f] reuses separated by 4 independent MFMAs)
    f32x4 sc[4] = {};
    __builtin_amdgcn_s_setprio(1);
#pragma unroll
    for (int ks = 0; ks < 4; ++ks) {
#pragma unroll
      for (int f = 0; f < 4; ++f) {
        int row = f*16 + lr;
        bf16x8 kf = *(const bf16x8*)(lKb + row*256 + ((ks*64 + lg*16) ^ ((row & 7) << 4)));
        sc[f] = __builtin_amdgcn_mfma_f32_16x16x32_bf16(qf[ks], kf, sc[f], 0, 0, 0);
      }
    }
    __builtin_amdgcn_s_setprio(0);
    if (kt < nt-1) STAGE_K(cur ^ 1, kt + 1);   // prefetch next K under softmax

    if (kt >= nt-2) {  // diagonal tiles only
#pragma unroll
      for (int f = 0; f < 4; ++f)
#pragma unroll
        for (int j = 0; j < 4; ++j)
          if (kt*64 + f*16 + lr > qt*128 + w*16 + lg*4 + j) sc[f][j] = -__builtin_inff();
    }
    // online softmax (base-2; log2e folded into Q)
    float rm[4], resc[4], rowp[4];
#pragma unroll
    for (int j = 0; j < 4; ++j) {
      rm[j] = fmaxf(fmaxf(sc[0][j], sc[1][j]), fmaxf(sc[2][j], sc[3][j]));
      rm[j] = fmaxf(rm[j], __shfl_xor(rm[j], 1, 64));
      rm[j] = fmaxf(rm[j], __shfl_xor(rm[j], 2, 64));
      rm[j] = fmaxf(rm[j], __shfl_xor(rm[j], 4, 64));
      rm[j] = fmaxf(rm[j], __shfl_xor(rm[j], 8, 64));
      float mn = fmaxf(m[j], rm[j]);
      resc[j] = exp2f(m[j] - mn);
      m[j] = mn;
      rowp[j] = 0.f;
    }
#pragma unroll
    for (int f = 0; f < 4; ++f)
#pragma unroll
      for (int j = 0; j < 4; ++j) {
        float p = exp2f(sc[f][j] - m[j]);
        sc[f][j] = p;
        rowp[j] += p;
      }
#pragma unroll
    for (int j = 0; j < 4; ++j) {
      rowp[j] += __shfl_xor(rowp[j], 1, 64);
      rowp[j] += __shfl_xor(rowp[j], 2, 64);
      rowp[j] += __shfl_xor(rowp[j], 4, 64);
      rowp[j] += __shfl_xor(rowp[j], 8, 64);
      ls[j] = ls[j] * resc[j] + rowp[j];
    }
#pragma unroll
    for (int fd = 0; fd < 8; ++fd)
#pragma unroll
      for (int j = 0; j < 4; ++j) oacc[fd][j] *= resc[j];
    // P -> wave-private LDS
#pragma unroll
    for (int f = 0; f < 4; ++f)
#pragma unroll
      for (int j = 0; j < 4; ++j)
        lP[w][(lg*4 + j)*72 + f*16 + lr] = f2bf(sc[f][j]);

    if (kt < nt-1) { asm volatile("s_waitcnt vmcnt(2)" ::: "memory"); }
    else           { asm volatile("s_waitcnt vmcnt(0)" ::: "memory"); }
    __builtin_amdgcn_s_barrier();
    asm volatile("" ::: "memory");
    // PV
    __builtin_amdgcn_s_setprio(1);
#pragma unroll
    for (int ks = 0; ks < 2; ++ks) {
      bf16x8 pf = *(const bf16x8*)((const char*)lP[w] + lr*144 + ks*64 + lg*16);
#pragma unroll
      for (int fd = 0; fd < 8; ++fd) {
        int row = fd*16 + lr;
        bf16x8 vf = *(const bf16x8*)((const char*)lV + row*128 + ((ks*64 + lg*16) ^ ((row & 7) << 4)));
        oacc[fd] = __builtin_amdgcn_mfma_f32_16x16x32_bf16(pf, vf, oacc[fd], 0, 0, 0);
      }
    }
    __builtin_amdgcn_s_setprio(0);
    asm volatile("" ::: "memory");
    __builtin_amdgcn_s_barrier();
    asm volatile("" ::: "memory");
    if (kt < nt-1) STAGE_V(kt + 1);
    cur ^= 1;
  }
#undef STAGE_K
#undef STAGE_V
  // epilogue
  float invl[4];
#pragma unroll
  for (int j = 0; j < 4; ++j) invl[j] = 1.0f / ls[j];
#pragma unroll
  for (int fd = 0; fd < 8; ++fd)
#pragma unroll
    for (int j = 0; j < 4; ++j) {
      int qq = qt*128 + w*16 + lg*4 + j;
      int dd = fd*16 + lr;
      float v = oacc[fd][j] * invl[j];
      AO[((size_t)b*S_ + qq)*D_ + h*HD_ + dd] = f2bf(v);
    }
}

// ---------------- launch ----------------
extern "C" void kernel_launch(void* const* d_in, const int* in_sizes, int n_in,
                              void* d_out, int out_size, void* d_ws, size_t ws_size,
                              hipStream_t stream) {
  const float* x        = (const float*)d_in[0];
  const float* w_qkv    = (const float*)d_in[1];
  const float* w_out    = (const float*)d_in[2];
  const float* attn_sc  = (const float*)d_in[3];
  const float* freqs    = (const float*)d_in[4];

  if (ws_size < 167772160u) return;  // need 160 MB scratch

  char* ws = (char*)d_ws;
  u16* xbf  = (u16*)(ws);                 //  16 MB  [4096][2048]
  u16* wqbf = (u16*)(ws + 16777216);      //  24 MB  [6144][2048]
  u16* wobf = (u16*)(ws + 41943040);      //   8 MB  [2048][2048]
  u16* qkv  = (u16*)(ws + 50331648);      //  48 MB  [4096][6144]
  u16* Qh   = (u16*)(ws + 100663296);     //  16 MB  [B*H][S][HD]
  u16* Kh   = (u16*)(ws + 117440512);     //  16 MB  [B*H][S][HD]
  u16* Vt   = (u16*)(ws + 134217728);     //  16 MB  [B*H][HD][S]
  u16* AO   = (u16*)(ws + 150994944);     //  16 MB  [4096][2048]

  castk<<<4096, 256, 0, stream>>>(x,     xbf,  8388608);
  castk<<<6144, 256, 0, stream>>>(w_qkv, wqbf, 12582912);
  castk<<<2048, 256, 0, stream>>>(w_out, wobf, 4194304);

  // QKV: 256x128 tiles -> (48, 16) = 768 blocks = 3 exact rounds of 256 CUs
  gemm8<1><<<dim3(48, 16), 512, 0, stream>>>(xbf, wqbf, qkv, 4096, 6144, 2048);

  rope_norm<<<16384, 256, 0, stream>>>(qkv, freqs, attn_sc, Qh, Kh);
  v_trans<<<1024, 256, 0, stream>>>(qkv, Vt);

  flash_attn<<<512, 512, 0, stream>>>(Qh, Kh, Vt, AO);

  // out-projection: 128x128 tiles, (16, 32) = 512 blocks, 2 blocks/CU
  gemm_bt<0><<<dim3(16, 32), 256, 0, stream>>>(AO, wobf, (float*)d_out, 4096, 2048, 2048);
}

// Round 10
// 278.145 us; speedup vs baseline: 1.2060x; 1.0565x over previous
//
#include <hip/hip_runtime.h>
#include <stdint.h>

#define B_  2
#define S_  2048
#define D_  2048
#define H_  16
#define HD_ 128
#define D3_ 6144

typedef unsigned short u16;
typedef __attribute__((ext_vector_type(8))) __bf16 bf16x8;
typedef __attribute__((ext_vector_type(4))) float f32x4;
typedef __attribute__((ext_vector_type(8))) u16  u16x8;
typedef __attribute__((ext_vector_type(4))) u16  u16x4;
typedef __attribute__((ext_vector_type(2))) u16  u16x2;

__device__ inline u16 f2bf(float f) {
  union { float f; uint32_t u; } v; v.f = f;
  uint32_t r = v.u + 0x7FFFu + ((v.u >> 16) & 1u);
  return (u16)(r >> 16);
}
__device__ inline float bf2f(u16 u) {
  union { float f; uint32_t u; } v; v.u = ((uint32_t)u) << 16;
  return v.f;
}
__device__ inline void gload_lds16(const void* g, void* l) {
  __builtin_amdgcn_global_load_lds((const __attribute__((address_space(1))) uint32_t*)g,
                                   (__attribute__((address_space(3))) uint32_t*)l, 16, 0, 0);
}

// tile-boundary sync: own ds_reads consumed, own staged gloads landed, barrier.
#define TILE_SYNC() do { \
    asm volatile("s_waitcnt lgkmcnt(0)" ::: "memory"); \
    asm volatile("s_waitcnt vmcnt(0)" ::: "memory"); \
    __builtin_amdgcn_s_barrier(); \
    asm volatile("" ::: "memory"); \
  } while (0)

// ---------------- fp32 -> bf16 cast ----------------
__global__ __launch_bounds__(256) void castk(const float* __restrict__ in, u16* __restrict__ out, int n) {
  int i = blockIdx.x * 256 + threadIdx.x;
  int n8 = n >> 3;
  if (i < n8) {
    f32x4 a = ((const f32x4*)in)[2*i];
    f32x4 b = ((const f32x4*)in)[2*i + 1];
    u16x8 o;
#pragma unroll
    for (int j = 0; j < 4; ++j) o[j] = f2bf(a[j]);
#pragma unroll
    for (int j = 0; j < 4; ++j) o[4+j] = f2bf(b[j]);
    ((u16x8*)out)[i] = o;
  }
}

// ============ B^T GEMM, BM=BN=256, BK=64, 8 waves (2M x 4N, wave 128x64).
// R8 geometry (best measured per-block util). One barrier per K-tile,
// straight-line interior, dep-split ks passes. LDS 128KB double-buffered. ============
template<int BF16OUT>
__global__ __launch_bounds__(512, 2) void gemm8(const u16* __restrict__ A, const u16* __restrict__ Bw,
                                                void* __restrict__ Cp, int M, int N, int K) {
  __shared__ __align__(16) u16 lds_[65536];   // 128 KB: A[2][32KB] | B[2][32KB]
  char* ldsb = (char*)lds_;
  const int tid = threadIdx.x;
  const int w = tid >> 6, l = tid & 63;
  const int lr = l & 15, lg = l >> 4;
  const int wr = w >> 2, wc = w & 3;          // 2 x 4 waves
  const int nbn = (int)gridDim.x;
  const int nwg = nbn * (int)gridDim.y;
  const int bid = (int)(blockIdx.y * gridDim.x + blockIdx.x);
  const int swz = (bid & 7) * (nwg >> 3) + (bid >> 3);   // XCD swizzle (nwg%8==0)
  const int bm = swz / nbn, bn = swz % nbn;

  f32x4 acc[8][4] = {};

  int row4[4], col4[4];
#pragma unroll
  for (int i = 0; i < 4; ++i) {
    int off = i*8192 + tid*16;
    row4[i] = off >> 7;                              // 0..255
    col4[i] = (off & 127) ^ ((row4[i] & 7) << 4);    // involution source swizzle
  }
  const size_t rs = (size_t)K * 2;
  const char* Ab = (const char*)A + (size_t)bm * 256 * rs;
  const char* Bb = (const char*)Bw + (size_t)bn * 256 * rs;
  const int wb = w * 1024;

#define STG(T_) do { \
    char* dA_ = ldsb + ((T_)&1)*32768; \
    char* dB_ = ldsb + 65536 + ((T_)&1)*32768; \
    _Pragma("unroll") \
    for (int i_ = 0; i_ < 4; ++i_) \
      gload_lds16(Ab + (size_t)row4[i_]*rs + (size_t)(T_)*128 + col4[i_], dA_ + i_*8192 + wb); \
    _Pragma("unroll") \
    for (int i_ = 0; i_ < 4; ++i_) \
      gload_lds16(Bb + (size_t)row4[i_]*rs + (size_t)(T_)*128 + col4[i_], dB_ + i_*8192 + wb); \
  } while (0)

#define RD_A(dst, mf, ks) do { int row_ = wr*128 + (mf)*16 + lr; \
    dst = *(const bf16x8*)(La + row_*128 + (((ks)*64 + lg*16) ^ ((row_ & 7) << 4))); } while (0)
#define RD_B(dst, nf, ks) do { int row_ = wc*64 + (nf)*16 + lr; \
    dst = *(const bf16x8*)(Lb + row_*128 + (((ks)*64 + lg*16) ^ ((row_ & 7) << 4))); } while (0)

  const int NT = K >> 6;
  STG(0);
  TILE_SYNC();

  for (int T = 0; T < NT; ++T) {
    const char* La = ldsb + (T & 1)*32768;
    const char* Lb = ldsb + 65536 + (T & 1)*32768;
    if (T + 1 < NT) STG(T + 1);          // 8 gloads into the inactive buffer

    bf16x8 a0[8], a1[8], b0[4], b1[4];
#pragma unroll
    for (int mf = 0; mf < 8; ++mf) { RD_A(a0[mf], mf, 0); RD_A(a1[mf], mf, 1); }
#pragma unroll
    for (int nf = 0; nf < 4; ++nf) { RD_B(b0[nf], nf, 0); RD_B(b1[nf], nf, 1); }
    // dep-split: all ks0 (32 independent), then all ks1
#pragma unroll
    for (int mf = 0; mf < 8; ++mf)
#pragma unroll
      for (int nf = 0; nf < 4; ++nf)
        acc[mf][nf] = __builtin_amdgcn_mfma_f32_16x16x32_bf16(a0[mf], b0[nf], acc[mf][nf], 0, 0, 0);
#pragma unroll
    for (int mf = 0; mf < 8; ++mf)
#pragma unroll
      for (int nf = 0; nf < 4; ++nf)
        acc[mf][nf] = __builtin_amdgcn_mfma_f32_16x16x32_bf16(a1[mf], b1[nf], acc[mf][nf], 0, 0, 0);
    TILE_SYNC();
  }
#undef STG
#undef RD_A
#undef RD_B

#pragma unroll
  for (int mf = 0; mf < 8; ++mf)
#pragma unroll
    for (int nf = 0; nf < 4; ++nf)
#pragma unroll
      for (int j = 0; j < 4; ++j) {
        int m = bm*256 + wr*128 + mf*16 + lg*4 + j;
        int n = bn*256 + wc*64 + nf*16 + lr;
        float v = acc[mf][nf][j];
        if (BF16OUT) ((u16*)Cp)[(size_t)m * N + n] = f2bf(v);
        else         ((float*)Cp)[(size_t)m * N + n] = v;
      }
}

// ---------------- 128x128 B^T GEMM, BK=64 dbuf, 1 barrier/K-tile, 2 blocks/CU ----------------
template<int BF16OUT>
__global__ __launch_bounds__(256, 2) void gemm_bt(const u16* __restrict__ A, const u16* __restrict__ Bw,
                                                  void* __restrict__ Cp, int M, int N, int K) {
  __shared__ __align__(16) u16 lds_[32768];   // 64 KB
  char* ldsb = (char*)lds_;
  const int tid = threadIdx.x;
  const int w = tid >> 6, l = tid & 63;
  const int lr = l & 15, lg = l >> 4;
  const int nwg = (int)(gridDim.x * gridDim.y);
  const int bid = (int)(blockIdx.y * gridDim.x + blockIdx.x);
  const int swz = (bid & 7) * (nwg >> 3) + (bid >> 3);
  const int bm = swz / (int)gridDim.x, bn = swz % (int)gridDim.x;
  const int wr = w >> 1, wc = w & 1;

  f32x4 acc[4][4] = {};

  int row4[4], col4[4];
#pragma unroll
  for (int i = 0; i < 4; ++i) {
    int off = i*4096 + tid*16;
    row4[i] = off >> 7;
    col4[i] = (off & 127) ^ ((row4[i] & 7) << 4);
  }
  const size_t rs = (size_t)K * 2;
  const char* Ab = (const char*)A + (size_t)bm * 128 * rs;
  const char* Bb = (const char*)Bw + (size_t)bn * 128 * rs;
  const int wb = w * 1024;

#define STG(T_) do { \
    char* dA_ = ldsb + ((T_)&1)*16384; \
    char* dB_ = ldsb + 32768 + ((T_)&1)*16384; \
    _Pragma("unroll") \
    for (int i_ = 0; i_ < 4; ++i_) \
      gload_lds16(Ab + (size_t)row4[i_]*rs + (size_t)(T_)*128 + col4[i_], dA_ + i_*4096 + wb); \
    _Pragma("unroll") \
    for (int i_ = 0; i_ < 4; ++i_) \
      gload_lds16(Bb + (size_t)row4[i_]*rs + (size_t)(T_)*128 + col4[i_], dB_ + i_*4096 + wb); \
  } while (0)

  const int NT = K >> 6;
  STG(0);
  TILE_SYNC();

  for (int T = 0; T < NT; ++T) {
    const char* La = ldsb + (T & 1)*16384;
    const char* Lb = ldsb + 32768 + (T & 1)*16384;
    if (T + 1 < NT) STG(T + 1);

    bf16x8 af[4][2], bf[4][2];
#pragma unroll
    for (int mt = 0; mt < 4; ++mt) {
      int row = wr*64 + mt*16 + lr;
#pragma unroll
      for (int ks = 0; ks < 2; ++ks)
        af[mt][ks] = *(const bf16x8*)(La + row*128 + ((ks*64 + lg*16) ^ ((row & 7) << 4)));
    }
#pragma unroll
    for (int nt = 0; nt < 4; ++nt) {
      int row = wc*64 + nt*16 + lr;
#pragma unroll
      for (int ks = 0; ks < 2; ++ks)
        bf[nt][ks] = *(const bf16x8*)(Lb + row*128 + ((ks*64 + lg*16) ^ ((row & 7) << 4)));
    }
#pragma unroll
    for (int mt = 0; mt < 4; ++mt)
#pragma unroll
      for (int nt = 0; nt < 4; ++nt)
        acc[mt][nt] = __builtin_amdgcn_mfma_f32_16x16x32_bf16(af[mt][0], bf[nt][0], acc[mt][nt], 0, 0, 0);
#pragma unroll
    for (int mt = 0; mt < 4; ++mt)
#pragma unroll
      for (int nt = 0; nt < 4; ++nt)
        acc[mt][nt] = __builtin_amdgcn_mfma_f32_16x16x32_bf16(af[mt][1], bf[nt][1], acc[mt][nt], 0, 0, 0);
    TILE_SYNC();
  }
#undef STG

#pragma unroll
  for (int mt = 0; mt < 4; ++mt)
#pragma unroll
    for (int nt = 0; nt < 4; ++nt)
#pragma unroll
      for (int j = 0; j < 4; ++j) {
        int m = bm*128 + wr*64 + mt*16 + lg*4 + j;
        int n = bn*128 + wc*64 + nt*16 + lr;
        float v = acc[mt][nt][j];
        if (BF16OUT) ((u16*)Cp)[(size_t)m * N + n] = f2bf(v);
        else         ((float*)Cp)[(size_t)m * N + n] = v;
      }
}

// ---------------- RoPE + per-head L2 norm (+attn_scale*log2e on Q) ----------------
__global__ __launch_bounds__(256) void rope_norm(const u16* __restrict__ qkv, const float* __restrict__ fc,
                                                 const float* __restrict__ scale_p,
                                                 u16* __restrict__ Qo, u16* __restrict__ Ko) {
  int gid = blockIdx.x;
  int bs = gid >> 2;
  int s = bs & (S_ - 1);
  int b = bs >> 11;
  int w = threadIdx.x >> 6, l = threadIdx.x & 63;
  int h = (gid & 3)*4 + w;
  float2 cs = ((const float2*)fc)[(size_t)s*64 + l];
  float scale = scale_p[0] * 1.4426950408889634f;  // fold log2(e) for exp2 softmax
  const u16* base = qkv + (size_t)bs * D3_;
  size_t obase = ((size_t)(b*H_ + h) * S_ + s) * HD_ + 2*l;
  {
    const u16* p = base + h*HD_ + 2*l;
    float x0 = bf2f(p[0]), x1 = bf2f(p[1]);
    float r0 = x0*cs.x - x1*cs.y;
    float r1 = x1*cs.x + x0*cs.y;
    float t = r0*r0 + r1*r1;
#pragma unroll
    for (int mk = 1; mk < 64; mk <<= 1) t += __shfl_xor(t, mk, 64);
    float inv = scale / (sqrtf(t) + 1e-6f);
    u16x2 o; o[0] = f2bf(r0*inv); o[1] = f2bf(r1*inv);
    *(u16x2*)(Qo + obase) = o;
  }
  {
    const u16* p = base + D_ + h*HD_ + 2*l;
    float x0 = bf2f(p[0]), x1 = bf2f(p[1]);
    float r0 = x0*cs.x - x1*cs.y;
    float r1 = x1*cs.x + x0*cs.y;
    float t = r0*r0 + r1*r1;
#pragma unroll
    for (int mk = 1; mk < 64; mk <<= 1) t += __shfl_xor(t, mk, 64);
    float inv = 1.0f / (sqrtf(t) + 1e-6f);
    u16x2 o; o[0] = f2bf(r0*inv); o[1] = f2bf(r1*inv);
    *(u16x2*)(Ko + obase) = o;
  }
}

// ---------------- V transpose: qkv v-slice [B,S,H,HD] -> Vt [B*H, HD, S] ----------------
__global__ __launch_bounds__(256) void v_trans(const u16* __restrict__ qkv, u16* __restrict__ Vt) {
  __shared__ u16 vt[64][136];
  int blk = blockIdx.x;
  int bh = blk >> 5, st = blk & 31;
  int b = bh >> 4, h = bh & 15;
  int s0 = st * 64;
  int tid = threadIdx.x;
#pragma unroll
  for (int i = 0; i < 4; ++i) {
    int idx = tid + i*256;
    int row = idx >> 4, ch = idx & 15;
    u16x8 v = *(const u16x8*)(qkv + (size_t)(b*S_ + s0 + row) * D3_ + 2*D_ + h*HD_ + ch*8);
    *(u16x8*)(&vt[row][ch*8]) = v;
  }
  __syncthreads();
#pragma unroll
  for (int p = 0; p < 2; ++p) {
    int d = p*64 + (tid >> 2);
    int q = (tid & 3) * 16;
    u16x8 t0, t1;
#pragma unroll
    for (int i = 0; i < 8; ++i) t0[i] = vt[q + i][d];
#pragma unroll
    for (int i = 0; i < 8; ++i) t1[i] = vt[q + 8 + i][d];
    u16* dst = Vt + ((size_t)bh * HD_ + d) * S_ + s0 + q;
    *(u16x8*)dst = t0;
    *(u16x8*)(dst + 8) = t1;
  }
}

// ---------------- causal flash attention (swapped QK^T, lane-local softmax) ----------------
// QBLK=128, 8 waves, KBLK=64. sc[f] = mfma(K_f, Q) -> sc[f][j] = S[k=f*16+lg*4+j][q=w*16+lr].
// Softmax per lane (q=lr): 15 in-lane ops + 2 shfl_xor; P packed to 4 ds_write_b64;
// 4 bpermutes redistribute rescale into oacc's j-space. K dbuf, V single-buf, counted vmcnt.
__global__ __launch_bounds__(512) void flash_attn(const u16* __restrict__ Qh, const u16* __restrict__ Kh,
                                                  const u16* __restrict__ Vt, u16* __restrict__ AO) {
  __shared__ __align__(16) u16 lK[2][64*128];   // 32 KB
  __shared__ __align__(16) u16 lV[128*64];      // 16 KB
  __shared__ __align__(16) u16 lP[8][16*72];    // 18 KB
  const int i0 = (int)blockIdx.x;               // 0..511
  const int k5 = i0 & 255;
  const int bh = k5 >> 3;
  const int jj = k5 & 7;
  const int qt = (i0 < 256) ? (15 - jj) : jj;   // heavy half first
  const int tid = threadIdx.x, w = tid >> 6, l = tid & 63;
  const int lr = l & 15, lg = l >> 4;
  const int b = bh >> 4, h = bh & 15;

  bf16x8 qf[4];
  {
    const u16* qp = Qh + ((size_t)bh * S_ + qt*128 + w*16 + lr) * HD_ + lg*8;
#pragma unroll
    for (int ks = 0; ks < 4; ++ks) qf[ks] = *(const bf16x8*)(qp + ks*32);
  }
  float m0 = -__builtin_inff(), ls0 = 0.f;      // running max/sum for q = w*16 + lr
  f32x4 oacc[8] = {};

  int krow[2], kcol[2], vrow[2], vcol[2], dstb[2];
#pragma unroll
  for (int p = 0; p < 2; ++p) {
    int off = p*8192 + tid*16;
    krow[p] = off >> 8; kcol[p] = (off & 255) ^ ((krow[p] & 7) << 4);
    vrow[p] = off >> 7; vcol[p] = (off & 127) ^ ((vrow[p] & 7) << 4);
    dstb[p] = p*8192 + w*1024;
  }
  const char* Kb = (const char*)(Kh + (size_t)bh * S_ * HD_);
  const char* Vb = (const char*)(Vt + (size_t)bh * HD_ * S_);

#define STAGE_K(nb, kt_) do {                                                       \
    _Pragma("unroll")                                                               \
    for (int p_ = 0; p_ < 2; ++p_)                                                  \
      gload_lds16(Kb + (size_t)((kt_)*64 + krow[p_])*256 + kcol[p_],                \
                  (char*)lK[nb] + dstb[p_]);                                        \
  } while (0)
#define STAGE_V(kt_) do {                                                           \
    _Pragma("unroll")                                                               \
    for (int p_ = 0; p_ < 2; ++p_)                                                  \
      gload_lds16(Vb + (size_t)vrow[p_]*(S_*2) + (kt_)*128 + vcol[p_],              \
                  (char*)lV + dstb[p_]);                                            \
  } while (0)

  const int nt = 2*qt + 2;
  STAGE_K(0, 0);
  STAGE_V(0);
  int cur = 0;
  for (int kt = 0; kt < nt; ++kt) {
    asm volatile("s_waitcnt vmcnt(2)" ::: "memory");
    __builtin_amdgcn_s_barrier();
    asm volatile("" ::: "memory");
    const char* lKb = (const char*)lK[cur];

    // swapped QK^T: sc[f][j] = S[k = kt*64 + f*16 + lg*4 + j][q = qt*128 + w*16 + lr]
    f32x4 sc[4] = {};
    __builtin_amdgcn_s_setprio(1);
#pragma unroll
    for (int ks = 0; ks < 4; ++ks) {
#pragma unroll
      for (int f = 0; f < 4; ++f) {
        int row = f*16 + lr;
        bf16x8 kf = *(const bf16x8*)(lKb + row*256 + ((ks*64 + lg*16) ^ ((row & 7) << 4)));
        sc[f] = __builtin_amdgcn_mfma_f32_16x16x32_bf16(kf, qf[ks], sc[f], 0, 0, 0);
      }
    }
    __builtin_amdgcn_s_setprio(0);
    if (kt < nt-1) STAGE_K(cur ^ 1, kt + 1);   // prefetch next K under softmax

    if (kt >= nt-2) {  // diagonal tiles: mask k > q
#pragma unroll
      for (int f = 0; f < 4; ++f)
#pragma unroll
        for (int j = 0; j < 4; ++j)
          if (kt*64 + f*16 + lg*4 + j > qt*128 + w*16 + lr) sc[f][j] = -__builtin_inff();
    }
    // lane-local online softmax (16 k-values in-lane, lg-groups via 2 shfl_xor)
    float pmax = sc[0][0];
#pragma unroll
    for (int f = 0; f < 4; ++f)
#pragma unroll
      for (int j = 0; j < 4; ++j) pmax = fmaxf(pmax, sc[f][j]);
    pmax = fmaxf(pmax, __shfl_xor(pmax, 16, 64));
    pmax = fmaxf(pmax, __shfl_xor(pmax, 32, 64));
    float mn = fmaxf(m0, pmax);
    float resc = exp2f(m0 - mn);
    m0 = mn;
    float rsum = 0.f;
#pragma unroll
    for (int f = 0; f < 4; ++f)
#pragma unroll
      for (int j = 0; j < 4; ++j) {
        float p = exp2f(sc[f][j] - mn);
        sc[f][j] = p;
        rsum += p;
      }
    rsum += __shfl_xor(rsum, 16, 64);
    rsum += __shfl_xor(rsum, 32, 64);
    ls0 = ls0 * resc + rsum;
    // redistribute resc from lr-space to j-space (q = w*16 + lg*4 + j)
    float rescj[4];
#pragma unroll
    for (int j = 0; j < 4; ++j) rescj[j] = __shfl(resc, lg*4 + j, 64);
#pragma unroll
    for (int fd = 0; fd < 8; ++fd)
#pragma unroll
      for (int j = 0; j < 4; ++j) oacc[fd][j] *= rescj[j];
    // P[q=lr][k] packed write: one b64 per f
#pragma unroll
    for (int f = 0; f < 4; ++f) {
      u16x4 pk;
#pragma unroll
      for (int j = 0; j < 4; ++j) pk[j] = f2bf(sc[f][j]);
      *(u16x4*)((char*)lP[w] + lr*144 + f*32 + lg*8) = pk;
    }

    if (kt < nt-1) { asm volatile("s_waitcnt vmcnt(2)" ::: "memory"); }
    else           { asm volatile("s_waitcnt vmcnt(0)" ::: "memory"); }
    __builtin_amdgcn_s_barrier();
    asm volatile("" ::: "memory");
    // PV (unchanged): oacc[fd] j-space rows q = w*16 + lg*4 + j
    __builtin_amdgcn_s_setprio(1);
#pragma unroll
    for (int ks = 0; ks < 2; ++ks) {
      bf16x8 pf = *(const bf16x8*)((const char*)lP[w] + lr*144 + ks*64 + lg*16);
#pragma unroll
      for (int fd = 0; fd < 8; ++fd) {
        int row = fd*16 + lr;
        bf16x8 vf = *(const bf16x8*)((const char*)lV + row*128 + ((ks*64 + lg*16) ^ ((row & 7) << 4)));
        oacc[fd] = __builtin_amdgcn_mfma_f32_16x16x32_bf16(pf, vf, oacc[fd], 0, 0, 0);
      }
    }
    __builtin_amdgcn_s_setprio(0);
    asm volatile("" ::: "memory");
    __builtin_amdgcn_s_barrier();
    asm volatile("" ::: "memory");
    if (kt < nt-1) STAGE_V(kt + 1);
    cur ^= 1;
  }
#undef STAGE_K
#undef STAGE_V
  // epilogue: 1/ls redistributed to j-space
  float invl[4];
#pragma unroll
  for (int j = 0; j < 4; ++j) {
    float lsj = __shfl(ls0, lg*4 + j, 64);
    invl[j] = 1.0f / lsj;
  }
#pragma unroll
  for (int fd = 0; fd < 8; ++fd)
#pragma unroll
    for (int j = 0; j < 4; ++j) {
      int qq = qt*128 + w*16 + lg*4 + j;
      int dd = fd*16 + lr;
      float v = oacc[fd][j] * invl[j];
      AO[((size_t)b*S_ + qq)*D_ + h*HD_ + dd] = f2bf(v);
    }
}

// ---------------- launch ----------------
extern "C" void kernel_launch(void* const* d_in, const int* in_sizes, int n_in,
                              void* d_out, int out_size, void* d_ws, size_t ws_size,
                              hipStream_t stream) {
  const float* x        = (const float*)d_in[0];
  const float* w_qkv    = (const float*)d_in[1];
  const float* w_out    = (const float*)d_in[2];
  const float* attn_sc  = (const float*)d_in[3];
  const float* freqs    = (const float*)d_in[4];

  if (ws_size < 167772160u) return;  // need 160 MB scratch

  char* ws = (char*)d_ws;
  u16* xbf  = (u16*)(ws);                 //  16 MB  [4096][2048]
  u16* wqbf = (u16*)(ws + 16777216);      //  24 MB  [6144][2048]
  u16* wobf = (u16*)(ws + 41943040);      //   8 MB  [2048][2048]
  u16* qkv  = (u16*)(ws + 50331648);      //  48 MB  [4096][6144]
  u16* Qh   = (u16*)(ws + 100663296);     //  16 MB  [B*H][S][HD]
  u16* Kh   = (u16*)(ws + 117440512);     //  16 MB  [B*H][S][HD]
  u16* Vt   = (u16*)(ws + 134217728);     //  16 MB  [B*H][HD][S]
  u16* AO   = (u16*)(ws + 150994944);     //  16 MB  [4096][2048]

  castk<<<4096, 256, 0, stream>>>(x,     xbf,  8388608);
  castk<<<6144, 256, 0, stream>>>(w_qkv, wqbf, 12582912);
  castk<<<2048, 256, 0, stream>>>(w_out, wobf, 4194304);

  // QKV: 256x256 tiles -> (24, 16) = 384 blocks
  gemm8<1><<<dim3(24, 16), 512, 0, stream>>>(xbf, wqbf, qkv, 4096, 6144, 2048);

  rope_norm<<<16384, 256, 0, stream>>>(qkv, freqs, attn_sc, Qh, Kh);
  v_trans<<<1024, 256, 0, stream>>>(qkv, Vt);

  flash_attn<<<512, 512, 0, stream>>>(Qh, Kh, Vt, AO);

  // out-projection: 128x128 tiles, (16, 32) = 512 blocks, 2 blocks/CU
  gemm_bt<0><<<dim3(16, 32), 256, 0, stream>>>(AO, wobf, (float*)d_out, 4096, 2048, 2048);
}